// Round 2
// baseline (782.480 us; speedup 1.0000x reference)
//
#include <hip/hip_runtime.h>
#include <cstddef>

#define B_ 4
#define N_ 20000
#define P_ 128
#define K_ 128
#define E_ 160000

constexpr int CHROWS = 256;
constexpr int NCHUNK = (N_ + CHROWS - 1) / CHROWS;  // 79

// ---------------------------------------------------------------------------
// x_spec partials: partial[b][c][k][p] = sum_{n in chunk c} evecs[b,n,k]*areas[b,n]*x_in[b,n,p]
// ---------------------------------------------------------------------------
__global__ __launch_bounds__(256)
void k_spec_partial(const float* __restrict__ evecs, const float* __restrict__ xin,
                    const float* __restrict__ areas, float* __restrict__ partial)
{
  const int c = blockIdx.x, b = blockIdx.y, t = threadIdx.x;
  const int ty = t >> 4, tx = t & 15;          // 16x16 threads
  __shared__ float ev[32][129];
  __shared__ float xs[32][129];
  float acc[8][8];
#pragma unroll
  for (int i = 0; i < 8; ++i)
#pragma unroll
    for (int j = 0; j < 8; ++j) acc[i][j] = 0.f;

  const float* evb = evecs + (size_t)b * N_ * K_;
  const float* xb  = xin   + (size_t)b * N_ * P_;
  const float* ab  = areas + (size_t)b * N_;

  for (int s = 0; s < CHROWS; s += 32) {
    const int n0 = c * CHROWS + s;
    __syncthreads();
#pragma unroll
    for (int i = 0; i < 4; ++i) {
      int f4 = t + i * 256;
      int r = f4 >> 5, c4 = (f4 & 31) << 2;
      int n = n0 + r;
      float4 e4 = make_float4(0.f,0.f,0.f,0.f), x4 = make_float4(0.f,0.f,0.f,0.f);
      float ar = 0.f;
      if (n < N_) {
        e4 = *(const float4*)(evb + (size_t)n * K_ + c4);
        x4 = *(const float4*)(xb  + (size_t)n * P_ + c4);
        ar = ab[n];
      }
      ev[r][c4+0] = e4.x*ar; ev[r][c4+1] = e4.y*ar; ev[r][c4+2] = e4.z*ar; ev[r][c4+3] = e4.w*ar;
      xs[r][c4+0] = x4.x;    xs[r][c4+1] = x4.y;    xs[r][c4+2] = x4.z;    xs[r][c4+3] = x4.w;
    }
    __syncthreads();
#pragma unroll 4
    for (int n = 0; n < 32; ++n) {
      float a[8], w[8];
#pragma unroll
      for (int i = 0; i < 8; ++i) a[i] = ev[n][ty*8 + i];
#pragma unroll
      for (int j = 0; j < 8; ++j) w[j] = xs[n][tx + 16*j];
#pragma unroll
      for (int i = 0; i < 8; ++i)
#pragma unroll
        for (int j = 0; j < 8; ++j) acc[i][j] = fmaf(a[i], w[j], acc[i][j]);
    }
  }
  float* po = partial + (size_t)(b * NCHUNK + c) * (K_ * P_);
#pragma unroll
  for (int i = 0; i < 8; ++i)
#pragma unroll
    for (int j = 0; j < 8; ++j)
      po[(ty*8 + i) * P_ + tx + 16*j] = acc[i][j];
}

// ---------------------------------------------------------------------------
// reduce partials, apply exp(-eval*time), write TRANSPOSED: sspecT[b][p][k]
// ---------------------------------------------------------------------------
__global__ __launch_bounds__(256)
void k_spec_reduce(const float* __restrict__ partial, const float* __restrict__ evals,
                   const float* __restrict__ times, float* __restrict__ sspecT)
{
  int idx = blockIdx.x * 256 + threadIdx.x;   // b*16384 + k*128 + p
  int b = idx >> 14;
  int kp = idx & 16383;
  int k = kp >> 7, p = kp & 127;
  float s = 0.f;
  const float* pb = partial + (size_t)b * NCHUNK * (K_*P_) + kp;
  for (int c = 0; c < NCHUNK; ++c) s += pb[(size_t)c * (K_*P_)];
  float tt = times[p]; tt = tt < 1e-8f ? 1e-8f : tt;
  float sc = __expf(-evals[b*K_ + k] * tt);
  sspecT[((size_t)b*P_ + p) * K_ + k] = s * sc;
}

// ---------------------------------------------------------------------------
// tiled row-GEMM: C[n,j] = sum_k A[n,k]*W[j,k]  (+epilogues), BM=128, BN=128, BK=128
// ---------------------------------------------------------------------------
__device__ __forceinline__ void stage_A(float (*As)[129], const float* A, int r0, int t)
{
#pragma unroll
  for (int i = 0; i < 8; ++i) {
    int f4 = t + i * 512;
    int r = f4 >> 5, c4 = (f4 & 31) << 2;
    int n = r0 + r;
    float4 v = make_float4(0.f,0.f,0.f,0.f);
    if (n < N_) v = *(const float4*)(A + (size_t)n * 128 + c4);
    As[r][c4+0] = v.x; As[r][c4+1] = v.y; As[r][c4+2] = v.z; As[r][c4+3] = v.w;
  }
}

__device__ __forceinline__ void stage_W(float (*Ws)[129], const float* W, int ldw, int kc, int t)
{
#pragma unroll
  for (int i = 0; i < 8; ++i) {
    int f4 = t + i * 512;
    int j = f4 >> 5, c4 = (f4 & 31) << 2;
    float4 v = *(const float4*)(W + (size_t)j * ldw + kc * 128 + c4);
    Ws[j][c4+0] = v.x; Ws[j][c4+1] = v.y; Ws[j][c4+2] = v.z; Ws[j][c4+3] = v.w;
  }
}

__device__ __forceinline__ void gemm_inner(const float (*As)[129], const float (*Ws)[129],
                                           int ty, int tx, float acc[8][4])
{
#pragma unroll 4
  for (int k = 0; k < 128; ++k) {
    float a[8], w[4];
#pragma unroll
    for (int i = 0; i < 8; ++i) a[i] = As[ty*8 + i][k];
#pragma unroll
    for (int j = 0; j < 4; ++j) w[j] = Ws[tx + 32*j][k];
#pragma unroll
    for (int i = 0; i < 8; ++i)
#pragma unroll
      for (int j = 0; j < 4; ++j) acc[i][j] = fmaf(a[i], w[j], acc[i][j]);
  }
}

// MODE: 0 plain, 1 relu+bias (3 chunks), 2 relu+bias (1 chunk), 3 bias+residual
template<int MODE>
__global__ __launch_bounds__(512)
void k_rowgemm(const float* __restrict__ A0, const float* __restrict__ A1,
               const float* __restrict__ A2, const float* __restrict__ W,
               int ldw, int wbs, int nchunk, const float* __restrict__ bias,
               const float* __restrict__ resid, float* __restrict__ C)
{
  const int b = blockIdx.y, r0 = blockIdx.x * 128, t = threadIdx.x;
  const int ty = t >> 5, tx = t & 31;   // ty 0..15 rows, tx 0..31 cols
  __shared__ float As[128][129];
  __shared__ float Ws[128][129];
  float acc[8][4];
#pragma unroll
  for (int i = 0; i < 8; ++i)
#pragma unroll
    for (int j = 0; j < 4; ++j) acc[i][j] = 0.f;

  const float* Wb = W + (size_t)b * wbs;   // batch-strided W (sspecT); 0 for shared weights

  for (int kc = 0; kc < nchunk; ++kc) {
    const float* A = (kc == 0 ? A0 : (kc == 1 ? A1 : A2)) + (size_t)b * N_ * 128;
    __syncthreads();
    stage_A(As, A, r0, t);
    stage_W(Ws, Wb, ldw, kc, t);
    __syncthreads();
    gemm_inner(As, Ws, ty, tx, acc);
  }

  const size_t cb = (size_t)b * N_ * 128;
#pragma unroll
  for (int i = 0; i < 8; ++i) {
    int n = r0 + ty*8 + i;
    if (n >= N_) continue;
#pragma unroll
    for (int j = 0; j < 4; ++j) {
      int col = tx + 32*j;
      float v = acc[i][j];
      if (MODE == 1 || MODE == 2) v = fmaxf(v + bias[col], 0.f);
      if (MODE == 3) v += bias[col] + resid[cb + (size_t)n*128 + col];
      C[cb + (size_t)n*128 + col] = v;
    }
  }
}

// ---------------------------------------------------------------------------
// grad features: gx <- tanh(gx*(gx@Bre^T) + gy*(gy@Bim^T)), in place over gx
// ---------------------------------------------------------------------------
__global__ __launch_bounds__(512)
void k_grad(const float* __restrict__ Bre, const float* __restrict__ Bim,
            float* __restrict__ gx, const float* __restrict__ gy)
{
  const int b = blockIdx.y, r0 = blockIdx.x * 128, t = threadIdx.x;
  const int ty = t >> 5, tx = t & 31;
  __shared__ float As[128][129];
  __shared__ float Ws[128][129];
  float acc1[8][4], acc2[8][4], g1[8][4];
#pragma unroll
  for (int i = 0; i < 8; ++i)
#pragma unroll
    for (int j = 0; j < 4; ++j) { acc1[i][j] = 0.f; acc2[i][j] = 0.f; }

  float*       gxb = gx + (size_t)b * N_ * P_;
  const float* gyb = gy + (size_t)b * N_ * P_;

  // pass 1: gx @ Bre^T
  stage_A(As, gxb, r0, t);
  stage_W(Ws, Bre, 128, 0, t);
  __syncthreads();
  gemm_inner(As, Ws, ty, tx, acc1);
#pragma unroll
  for (int i = 0; i < 8; ++i)
#pragma unroll
    for (int j = 0; j < 4; ++j) g1[i][j] = As[ty*8 + i][tx + 32*j];
  __syncthreads();
  // pass 2: gy @ Bim^T
  stage_A(As, gyb, r0, t);
  stage_W(Ws, Bim, 128, 0, t);
  __syncthreads();
  gemm_inner(As, Ws, ty, tx, acc2);

#pragma unroll
  for (int i = 0; i < 8; ++i) {
    int n = r0 + ty*8 + i;
    if (n >= N_) continue;
#pragma unroll
    for (int j = 0; j < 4; ++j) {
      int col = tx + 32*j;
      float g2 = As[ty*8 + i][col];
      gxb[(size_t)n*P_ + col] = tanhf(g1[i][j]*acc1[i][j] + g2*acc2[i][j]);
    }
  }
}

// ---------------------------------------------------------------------------
// SpMM via counting sort: count -> scan -> fill bins -> gather (wave per row)
// ---------------------------------------------------------------------------
__global__ void k_count(const int* __restrict__ rows, int* __restrict__ cnt)
{
  int b = blockIdx.y;
  int e = blockIdx.x * 256 + threadIdx.x;
  if (e < E_) atomicAdd(&cnt[b*N_ + rows[(size_t)b*E_ + e]], 1);
}

__global__ __launch_bounds__(256)
void k_scan(const int* __restrict__ cnt, int* __restrict__ off, int* __restrict__ pos)
{
  const int b = blockIdx.x, t = threadIdx.x;
  const int lane = t & 63, wid = t >> 6;
  __shared__ int wt[4];
  int running = 0;
  for (int base = 0; base < N_; base += 256) {
    int i = base + t;
    int v = (i < N_) ? cnt[b*N_ + i] : 0;
    int x = v;
#pragma unroll
    for (int ofs = 1; ofs < 64; ofs <<= 1) {
      int y = __shfl_up(x, ofs, 64);
      if (lane >= ofs) x += y;
    }
    if (lane == 63) wt[wid] = x;
    __syncthreads();
    int wofs = 0;
    for (int wj = 0; wj < wid; ++wj) wofs += wt[wj];
    int tot = wt[0] + wt[1] + wt[2] + wt[3];
    int excl = running + wofs + x - v;
    if (i < N_) { off[b*(N_+1) + i] = excl; pos[b*N_ + i] = excl; }
    running += tot;
    __syncthreads();
  }
  if (t == 0) off[b*(N_+1) + N_] = running;
}

__global__ void k_fill(const int* __restrict__ rows, int* __restrict__ pos,
                       int* __restrict__ bins)
{
  int b = blockIdx.y;
  int e = blockIdx.x * 256 + threadIdx.x;
  if (e < E_) {
    int r = rows[(size_t)b*E_ + e];
    int p = atomicAdd(&pos[b*N_ + r], 1);
    bins[(size_t)b*E_ + p] = e;
  }
}

__global__ __launch_bounds__(256)
void k_gather(const float* __restrict__ xd, const float* __restrict__ vx,
              const float* __restrict__ vy, const int* __restrict__ cols,
              const int* __restrict__ bins, const int* __restrict__ off,
              float* __restrict__ gx, float* __restrict__ gy)
{
  const int b = blockIdx.y;
  const int row = (blockIdx.x * 256 + threadIdx.x) >> 6;  // wave per row
  const int lane = threadIdx.x & 63;
  if (row >= N_) return;
  const int s = off[b*(N_+1) + row], e = off[b*(N_+1) + row + 1];
  float ax0 = 0.f, ax1 = 0.f, ay0 = 0.f, ay1 = 0.f;
  const float* xdb = xd + (size_t)b * N_ * P_;
  for (int i = s; i < e; ++i) {
    int ed   = bins[(size_t)b*E_ + i];
    int cidx = cols[(size_t)b*E_ + ed];
    float wx = vx[(size_t)b*E_ + ed];
    float wy = vy[(size_t)b*E_ + ed];
    float2 xv = *(const float2*)(xdb + (size_t)cidx*P_ + lane*2);
    ax0 = fmaf(wx, xv.x, ax0); ax1 = fmaf(wx, xv.y, ax1);
    ay0 = fmaf(wy, xv.x, ay0); ay1 = fmaf(wy, xv.y, ay1);
  }
  size_t o = (size_t)b * N_ * P_ + (size_t)row * P_ + lane*2;
  *(float2*)(gx + o) = make_float2(ax0, ax1);
  *(float2*)(gy + o) = make_float2(ay0, ay1);
}

// ---------------------------------------------------------------------------
extern "C" void kernel_launch(void* const* d_in, const int* in_sizes, int n_in,
                              void* d_out, int out_size, void* d_ws, size_t ws_size,
                              hipStream_t stream)
{
  const float* x_in  = (const float*)d_in[0];
  const float* areas = (const float*)d_in[1];
  const float* evals = (const float*)d_in[2];
  const float* evecs = (const float*)d_in[3];
  const float* gXv   = (const float*)d_in[4];
  const float* gYv   = (const float*)d_in[5];
  const int*   grows = (const int*)d_in[6];
  const int*   gcols = (const int*)d_in[7];
  const float* times = (const float*)d_in[8];
  const float* Bre   = (const float*)d_in[9];
  const float* Bim   = (const float*)d_in[10];
  const float* W1    = (const float*)d_in[11];
  const float* b1    = (const float*)d_in[12];
  const float* W2    = (const float*)d_in[13];
  const float* b2    = (const float*)d_in[14];
  const float* W3    = (const float*)d_in[15];
  const float* b3    = (const float*)d_in[16];

  float* ws    = (float*)d_ws;
  float* xd    = ws;                        // B*N*P = 10,240,000 floats
  float* slotA = ws + 10240000;             // spec partials -> gx -> x_grad
  float* slotB = ws + 20480000;             // gy -> h2
  float* out   = (float*)d_out;

  // transient scratch lives in d_out's tail; all dead before MLP1 writes out
  int*   ipos   = (int*)d_out;              // B*N counts / cursor
  int*   ioff   = ipos + B_*N_;             // B*(N+1) offsets
  int*   ibins  = ioff + B_*(N_+1);         // B*E binned edge ids
  float* sspecT = (float*)(ibins + (size_t)B_*E_);  // B*P*K = 65,536 floats

  const int GB = (N_ + 127) / 128;  // 157 row blocks

  // spectral projection + scale (fused, transposed output)
  k_spec_partial<<<dim3(NCHUNK, B_), 256, 0, stream>>>(evecs, x_in, areas, slotA);
  k_spec_reduce<<<dim3(B_*K_*P_/256), 256, 0, stream>>>(slotA, evals, times, sspecT);
  // x_diffuse = evecs @ sspec   (W is per-batch: wbs = K*P)
  k_rowgemm<0><<<dim3(GB, B_), 512, 0, stream>>>(evecs, nullptr, nullptr, sspecT,
                                                 128, K_*P_, 1, nullptr, nullptr, xd);
  // sparse gradient via counting sort
  hipMemsetAsync(ipos, 0, (size_t)B_*N_*sizeof(int), stream);
  k_count<<<dim3(E_/256, B_), 256, 0, stream>>>(grows, ipos);
  k_scan<<<dim3(B_), 256, 0, stream>>>(ipos, ioff, ipos);
  k_fill<<<dim3(E_/256, B_), 256, 0, stream>>>(grows, ipos, ibins);
  k_gather<<<dim3(N_/4, B_), 256, 0, stream>>>(xd, gXv, gYv, gcols, ibins, ioff,
                                               slotA, slotB);
  // grad features (in place over slotA)
  k_grad<<<dim3(GB, B_), 512, 0, stream>>>(Bre, Bim, slotA, slotB);
  // MLP
  k_rowgemm<1><<<dim3(GB, B_), 512, 0, stream>>>(x_in, xd, slotA, W1, 384, 0, 3, b1,
                                                 nullptr, out);
  k_rowgemm<2><<<dim3(GB, B_), 512, 0, stream>>>(out, nullptr, nullptr, W2, 128, 0, 1,
                                                 b2, nullptr, slotB);
  k_rowgemm<3><<<dim3(GB, B_), 512, 0, stream>>>(slotB, nullptr, nullptr, W3, 128, 0, 1,
                                                 b3, x_in, out);
}

// Round 3
// 439.605 us; speedup vs baseline: 1.7800x; 1.7800x over previous
//
#include <hip/hip_runtime.h>
#include <hip/hip_bf16.h>
#include <cstddef>

#define B_ 4
#define N_ 20000
#define P_ 128
#define K_ 128
#define E_ 160000

constexpr int CHROWS = 256;
constexpr int NCHUNK = (N_ + CHROWS - 1) / CHROWS;  // 79

typedef __attribute__((ext_vector_type(8))) short short8;
typedef __attribute__((ext_vector_type(4))) float f32x4;

__device__ __forceinline__ unsigned pk2(float x, float y) {
  __hip_bfloat162 h = __float22bfloat162_rn(make_float2(x, y));  // RNE pack
  union { __hip_bfloat162 h; unsigned u; } c; c.h = h; return c.u;
}
__device__ __forceinline__ float bf2f(short s) {
  union { unsigned u; float f; } c; c.u = ((unsigned)(unsigned short)s) << 16; return c.f;
}

// ---------------------------------------------------------------------------
// x_spec partials (fp32): partial[b][c][k][p] = sum_n evecs[b,n,k]*area*x_in[b,n,p]
// ---------------------------------------------------------------------------
__global__ __launch_bounds__(256)
void k_spec_partial(const float* __restrict__ evecs, const float* __restrict__ xin,
                    const float* __restrict__ areas, float* __restrict__ partial)
{
  const int c = blockIdx.x, b = blockIdx.y, t = threadIdx.x;
  const int ty = t >> 4, tx = t & 15;
  __shared__ float ev[32][129];
  __shared__ float xs[32][129];
  float acc[8][8];
#pragma unroll
  for (int i = 0; i < 8; ++i)
#pragma unroll
    for (int j = 0; j < 8; ++j) acc[i][j] = 0.f;

  const float* evb = evecs + (size_t)b * N_ * K_;
  const float* xb  = xin   + (size_t)b * N_ * P_;
  const float* ab  = areas + (size_t)b * N_;

  for (int s = 0; s < CHROWS; s += 32) {
    const int n0 = c * CHROWS + s;
    __syncthreads();
#pragma unroll
    for (int i = 0; i < 4; ++i) {
      int f4 = t + i * 256;
      int r = f4 >> 5, c4 = (f4 & 31) << 2;
      int n = n0 + r;
      float4 e4 = make_float4(0.f,0.f,0.f,0.f), x4 = make_float4(0.f,0.f,0.f,0.f);
      float ar = 0.f;
      if (n < N_) {
        e4 = *(const float4*)(evb + (size_t)n * K_ + c4);
        x4 = *(const float4*)(xb  + (size_t)n * P_ + c4);
        ar = ab[n];
      }
      ev[r][c4+0] = e4.x*ar; ev[r][c4+1] = e4.y*ar; ev[r][c4+2] = e4.z*ar; ev[r][c4+3] = e4.w*ar;
      xs[r][c4+0] = x4.x;    xs[r][c4+1] = x4.y;    xs[r][c4+2] = x4.z;    xs[r][c4+3] = x4.w;
    }
    __syncthreads();
#pragma unroll 4
    for (int n = 0; n < 32; ++n) {
      float a[8], w[8];
#pragma unroll
      for (int i = 0; i < 8; ++i) a[i] = ev[n][ty*8 + i];
#pragma unroll
      for (int j = 0; j < 8; ++j) w[j] = xs[n][tx + 16*j];
#pragma unroll
      for (int i = 0; i < 8; ++i)
#pragma unroll
        for (int j = 0; j < 8; ++j) acc[i][j] = fmaf(a[i], w[j], acc[i][j]);
    }
  }
  float* po = partial + (size_t)(b * NCHUNK + c) * (K_ * P_);
#pragma unroll
  for (int i = 0; i < 8; ++i)
#pragma unroll
    for (int j = 0; j < 8; ++j)
      po[(ty*8 + i) * P_ + tx + 16*j] = acc[i][j];
}

__global__ __launch_bounds__(256)
void k_spec_reduce(const float* __restrict__ partial, const float* __restrict__ evals,
                   const float* __restrict__ times, float* __restrict__ sspecT)
{
  int idx = blockIdx.x * 256 + threadIdx.x;
  int b = idx >> 14;
  int kp = idx & 16383;
  int k = kp >> 7, p = kp & 127;
  float s = 0.f;
  const float* pb = partial + (size_t)b * NCHUNK * (K_*P_) + kp;
  for (int c = 0; c < NCHUNK; ++c) s += pb[(size_t)c * (K_*P_)];
  float tt = times[p]; tt = tt < 1e-8f ? 1e-8f : tt;
  float sc = __expf(-evals[b*K_ + k] * tt);
  sspecT[((size_t)b*P_ + p) * K_ + k] = s * sc;
}

// ---------------------------------------------------------------------------
// bf16 MFMA row-GEMM machinery.
// LDS tile: 128 rows x 16 kgroups (8 bf16 = 16B each), slot = r*16 + (kg ^ (r&7))
// (XOR swizzle: linear 256B-stride rows would be a 32-way bank conflict on the
//  16-row fragment read; swizzle makes it 2-way = free.)
// ---------------------------------------------------------------------------
__device__ __forceinline__ void stg(uint4* __restrict__ Ls, const float* __restrict__ G,
                                    int ld, int nrows, int t)
{
#pragma unroll
  for (int i = 0; i < 4; ++i) {
    int gid = t + i * 512;
    int r = gid >> 4, kg = gid & 15;
    float4 v0 = make_float4(0.f,0.f,0.f,0.f), v1 = v0;
    if (r < nrows) {
      const float* p = G + (size_t)r * ld + kg * 8;
      v0 = *(const float4*)p;
      v1 = *(const float4*)(p + 4);
    }
    uint4 u;
    u.x = pk2(v0.x, v0.y); u.y = pk2(v0.z, v0.w);
    u.z = pk2(v1.x, v1.y); u.w = pk2(v1.z, v1.w);
    Ls[r * 16 + (kg ^ (r & 7))] = u;
  }
}

// one 128-K chunk of MFMA: wave (wr,wc) accumulates its 64x32 sub-tile
__device__ __forceinline__ void mfma_chunk(const uint4* AsB, const uint4* WsB,
                                           int wr, int wc, int lr, int lg,
                                           f32x4 acc[4][2])
{
  const short8* Ap = (const short8*)AsB;
  const short8* Wp = (const short8*)WsB;
#pragma unroll
  for (int kk = 0; kk < 4; ++kk) {
    int gg = kk * 4 + lg;
    short8 a[4], w[2];
#pragma unroll
    for (int m = 0; m < 4; ++m) {
      int rr = wr*64 + m*16 + lr;
      a[m] = Ap[rr*16 + (gg ^ (rr & 7))];
    }
#pragma unroll
    for (int n = 0; n < 2; ++n) {
      int rr = wc*32 + n*16 + lr;
      w[n] = Wp[rr*16 + (gg ^ (rr & 7))];
    }
#pragma unroll
    for (int m = 0; m < 4; ++m)
#pragma unroll
      for (int n = 0; n < 2; ++n)
        acc[m][n] = __builtin_amdgcn_mfma_f32_16x16x32_bf16(a[m], w[n], acc[m][n], 0, 0, 0);
  }
}

// MODE: 0 plain, 1 relu+bias (3 chunks), 2 relu+bias, 3 bias+residual
template<int MODE>
__global__ __launch_bounds__(512)
void k_rowgemm(const float* __restrict__ A0, const float* __restrict__ A1,
               const float* __restrict__ A2, const float* __restrict__ W,
               int ldw, int wbs, int nchunk, const float* __restrict__ bias,
               const float* __restrict__ resid, float* __restrict__ C)
{
  const int b = blockIdx.y, r0 = blockIdx.x * 128, t = threadIdx.x;
  const int l = t & 63, wid = t >> 6;
  const int wr = wid >> 2, wc = wid & 3;          // 2x4 wave grid
  const int lr = l & 15, lg = l >> 4;
  __shared__ uint4 AsB[2048];
  __shared__ uint4 WsB[2048];
  f32x4 acc[4][2];
#pragma unroll
  for (int m = 0; m < 4; ++m)
#pragma unroll
    for (int n = 0; n < 2; ++n) acc[m][n] = (f32x4)0.f;

  const float* Wb = W + (size_t)b * wbs;
  const int nrows = min(128, N_ - r0);

  for (int kc = 0; kc < nchunk; ++kc) {
    const float* A = (kc == 0 ? A0 : (kc == 1 ? A1 : A2))
                     + (size_t)b * N_ * 128 + (size_t)r0 * 128;
    __syncthreads();
    stg(AsB, A, 128, nrows, t);
    stg(WsB, Wb + kc * 128, ldw, 128, t);
    __syncthreads();
    mfma_chunk(AsB, WsB, wr, wc, lr, lg, acc);
  }

  const size_t cb = (size_t)b * N_ * 128;
#pragma unroll
  for (int m = 0; m < 4; ++m) {
    int rowt = wr*64 + m*16 + lg*4;
#pragma unroll
    for (int r = 0; r < 4; ++r) {
      int row = r0 + rowt + r;
      if (row >= N_) continue;
#pragma unroll
      for (int n = 0; n < 2; ++n) {
        int col = wc*32 + n*16 + lr;
        float v = acc[m][n][r];
        if (MODE == 1 || MODE == 2) v = fmaxf(v + bias[col], 0.f);
        if (MODE == 3) v += bias[col] + resid[cb + (size_t)row*128 + col];
        C[cb + (size_t)row*128 + col] = v;
      }
    }
  }
}

// ---------------------------------------------------------------------------
// grad features (MFMA): gx <- tanh(gx*(gx@Bre^T) + gy*(gy@Bim^T)), in place
// ---------------------------------------------------------------------------
__global__ __launch_bounds__(512)
void k_grad(const float* __restrict__ Bre, const float* __restrict__ Bim,
            float* __restrict__ gx, const float* __restrict__ gy)
{
  const int b = blockIdx.y, r0 = blockIdx.x * 128, t = threadIdx.x;
  const int l = t & 63, wid = t >> 6;
  const int wr = wid >> 2, wc = wid & 3;
  const int lr = l & 15, lg = l >> 4;
  __shared__ uint4 AsB[2048];
  __shared__ uint4 WsB[2048];
  f32x4 acc1[4][2], acc2[4][2];
  float g1[4][2][4], g2[4][2][4];
#pragma unroll
  for (int m = 0; m < 4; ++m)
#pragma unroll
    for (int n = 0; n < 2; ++n) { acc1[m][n] = (f32x4)0.f; acc2[m][n] = (f32x4)0.f; }

  float*       gxb = gx + (size_t)b * N_ * P_;
  const float* gyb = gy + (size_t)b * N_ * P_;
  const int nrows = min(128, N_ - r0);
  const short* Ab = (const short*)AsB;

  // pass 1: gx @ Bre^T
  stg(AsB, gxb + (size_t)r0 * 128, 128, nrows, t);
  stg(WsB, Bre, 128, 128, t);
  __syncthreads();
  mfma_chunk(AsB, WsB, wr, wc, lr, lg, acc1);
  // pick up gx values at this lane's C positions (bf16-rounded; fine for gate)
#pragma unroll
  for (int m = 0; m < 4; ++m)
#pragma unroll
    for (int r = 0; r < 4; ++r) {
      int rowt = wr*64 + m*16 + lg*4 + r;
#pragma unroll
      for (int n = 0; n < 2; ++n) {
        int col = wc*32 + n*16 + lr;
        g1[m][n][r] = bf2f(Ab[(rowt*16 + ((col>>3) ^ (rowt & 7)))*8 + (col & 7)]);
      }
    }
  __syncthreads();   // all reads done before restage
  // pass 2: gy @ Bim^T
  stg(AsB, gyb + (size_t)r0 * 128, 128, nrows, t);
  stg(WsB, Bim, 128, 128, t);
  __syncthreads();
  mfma_chunk(AsB, WsB, wr, wc, lr, lg, acc2);
#pragma unroll
  for (int m = 0; m < 4; ++m)
#pragma unroll
    for (int r = 0; r < 4; ++r) {
      int rowt = wr*64 + m*16 + lg*4 + r;
#pragma unroll
      for (int n = 0; n < 2; ++n) {
        int col = wc*32 + n*16 + lr;
        g2[m][n][r] = bf2f(Ab[(rowt*16 + ((col>>3) ^ (rowt & 7)))*8 + (col & 7)]);
      }
    }

#pragma unroll
  for (int m = 0; m < 4; ++m)
#pragma unroll
    for (int r = 0; r < 4; ++r) {
      int row = r0 + wr*64 + m*16 + lg*4 + r;
      if (row >= N_) continue;
#pragma unroll
      for (int n = 0; n < 2; ++n) {
        int col = wc*32 + n*16 + lr;
        gxb[(size_t)row*128 + col] =
            tanhf(g1[m][n][r]*acc1[m][n][r] + g2[m][n][r]*acc2[m][n][r]);
      }
    }
}

// ---------------------------------------------------------------------------
// SpMM via counting sort: count -> scan -> fill bins -> gather (wave per row)
// ---------------------------------------------------------------------------
__global__ void k_count(const int* __restrict__ rows, int* __restrict__ cnt)
{
  int b = blockIdx.y;
  int e = blockIdx.x * 256 + threadIdx.x;
  if (e < E_) atomicAdd(&cnt[b*N_ + rows[(size_t)b*E_ + e]], 1);
}

__global__ __launch_bounds__(256)
void k_scan(const int* __restrict__ cnt, int* __restrict__ off, int* __restrict__ pos)
{
  const int b = blockIdx.x, t = threadIdx.x;
  const int lane = t & 63, wid = t >> 6;
  __shared__ int wt[4];
  int running = 0;
  for (int base = 0; base < N_; base += 256) {
    int i = base + t;
    int v = (i < N_) ? cnt[b*N_ + i] : 0;
    int x = v;
#pragma unroll
    for (int ofs = 1; ofs < 64; ofs <<= 1) {
      int y = __shfl_up(x, ofs, 64);
      if (lane >= ofs) x += y;
    }
    if (lane == 63) wt[wid] = x;
    __syncthreads();
    int wofs = 0;
    for (int wj = 0; wj < wid; ++wj) wofs += wt[wj];
    int tot = wt[0] + wt[1] + wt[2] + wt[3];
    int excl = running + wofs + x - v;
    if (i < N_) { off[b*(N_+1) + i] = excl; pos[b*N_ + i] = excl; }
    running += tot;
    __syncthreads();
  }
  if (t == 0) off[b*(N_+1) + N_] = running;
}

__global__ void k_fill(const int* __restrict__ rows, int* __restrict__ pos,
                       int* __restrict__ bins)
{
  int b = blockIdx.y;
  int e = blockIdx.x * 256 + threadIdx.x;
  if (e < E_) {
    int r = rows[(size_t)b*E_ + e];
    int p = atomicAdd(&pos[b*N_ + r], 1);
    bins[(size_t)b*E_ + p] = e;
  }
}

__global__ __launch_bounds__(256)
void k_gather(const float* __restrict__ xd, const float* __restrict__ vx,
              const float* __restrict__ vy, const int* __restrict__ cols,
              const int* __restrict__ bins, const int* __restrict__ off,
              float* __restrict__ gx, float* __restrict__ gy)
{
  const int b = blockIdx.y;
  const int row = (blockIdx.x * 256 + threadIdx.x) >> 6;  // wave per row
  const int lane = threadIdx.x & 63;
  if (row >= N_) return;
  const int s = off[b*(N_+1) + row], e = off[b*(N_+1) + row + 1];
  float ax0 = 0.f, ax1 = 0.f, ay0 = 0.f, ay1 = 0.f;
  const float* xdb = xd + (size_t)b * N_ * P_;
  for (int i = s; i < e; ++i) {
    int ed   = bins[(size_t)b*E_ + i];
    int cidx = cols[(size_t)b*E_ + ed];
    float wx = vx[(size_t)b*E_ + ed];
    float wy = vy[(size_t)b*E_ + ed];
    float2 xv = *(const float2*)(xdb + (size_t)cidx*P_ + lane*2);
    ax0 = fmaf(wx, xv.x, ax0); ax1 = fmaf(wx, xv.y, ax1);
    ay0 = fmaf(wy, xv.x, ay0); ay1 = fmaf(wy, xv.y, ay1);
  }
  size_t o = (size_t)b * N_ * P_ + (size_t)row * P_ + lane*2;
  *(float2*)(gx + o) = make_float2(ax0, ax1);
  *(float2*)(gy + o) = make_float2(ay0, ay1);
}

// ---------------------------------------------------------------------------
extern "C" void kernel_launch(void* const* d_in, const int* in_sizes, int n_in,
                              void* d_out, int out_size, void* d_ws, size_t ws_size,
                              hipStream_t stream)
{
  const float* x_in  = (const float*)d_in[0];
  const float* areas = (const float*)d_in[1];
  const float* evals = (const float*)d_in[2];
  const float* evecs = (const float*)d_in[3];
  const float* gXv   = (const float*)d_in[4];
  const float* gYv   = (const float*)d_in[5];
  const int*   grows = (const int*)d_in[6];
  const int*   gcols = (const int*)d_in[7];
  const float* times = (const float*)d_in[8];
  const float* Bre   = (const float*)d_in[9];
  const float* Bim   = (const float*)d_in[10];
  const float* W1    = (const float*)d_in[11];
  const float* b1    = (const float*)d_in[12];
  const float* W2    = (const float*)d_in[13];
  const float* b2    = (const float*)d_in[14];
  const float* W3    = (const float*)d_in[15];
  const float* b3    = (const float*)d_in[16];

  float* ws    = (float*)d_ws;
  float* xd    = ws;                        // B*N*P floats
  float* slotA = ws + 10240000;             // spec partials -> gx -> x_grad
  float* slotB = ws + 20480000;             // gy -> h2
  float* out   = (float*)d_out;

  // transient scratch in d_out's tail; dead before MLP1 writes out
  int*   ipos   = (int*)d_out;              // B*N counts / cursor
  int*   ioff   = ipos + B_*N_;             // B*(N+1) offsets
  int*   ibins  = ioff + B_*(N_+1);         // B*E binned edge ids
  float* sspecT = (float*)(ibins + (size_t)B_*E_);  // B*P*K floats

  const int GB = (N_ + 127) / 128;  // 157 row blocks

  // spectral projection + scale (fused, transposed output)
  k_spec_partial<<<dim3(NCHUNK, B_), 256, 0, stream>>>(evecs, x_in, areas, slotA);
  k_spec_reduce<<<dim3(B_*K_*P_/256), 256, 0, stream>>>(slotA, evals, times, sspecT);
  // x_diffuse = evecs @ sspec   (W per-batch: wbs = K*P)
  k_rowgemm<0><<<dim3(GB, B_), 512, 0, stream>>>(evecs, nullptr, nullptr, sspecT,
                                                 128, K_*P_, 1, nullptr, nullptr, xd);
  // sparse gradient via counting sort
  hipMemsetAsync(ipos, 0, (size_t)B_*N_*sizeof(int), stream);
  k_count<<<dim3(E_/256, B_), 256, 0, stream>>>(grows, ipos);
  k_scan<<<dim3(B_), 256, 0, stream>>>(ipos, ioff, ipos);
  k_fill<<<dim3(E_/256, B_), 256, 0, stream>>>(grows, ipos, ibins);
  k_gather<<<dim3(N_/4, B_), 256, 0, stream>>>(xd, gXv, gYv, gcols, ibins, ioff,
                                               slotA, slotB);
  // grad features (in place over slotA)
  k_grad<<<dim3(GB, B_), 512, 0, stream>>>(Bre, Bim, slotA, slotB);
  // MLP
  k_rowgemm<1><<<dim3(GB, B_), 512, 0, stream>>>(x_in, xd, slotA, W1, 384, 0, 3, b1,
                                                 nullptr, out);
  k_rowgemm<2><<<dim3(GB, B_), 512, 0, stream>>>(out, nullptr, nullptr, W2, 128, 0, 1,
                                                 b2, nullptr, slotB);
  k_rowgemm<3><<<dim3(GB, B_), 512, 0, stream>>>(slotB, nullptr, nullptr, W3, 128, 0, 1,
                                                 b3, x_in, out);
}

// Round 4
// 372.299 us; speedup vs baseline: 2.1018x; 1.1808x over previous
//
#include <hip/hip_runtime.h>
#include <hip/hip_bf16.h>
#include <cstddef>

#define B_ 4
#define N_ 20000
#define P_ 128
#define K_ 128
#define E_ 160000

constexpr int CHROWS = 256;
constexpr int NCHUNK = (N_ + CHROWS - 1) / CHROWS;  // 79

typedef __attribute__((ext_vector_type(8))) short short8;
typedef __attribute__((ext_vector_type(4))) float f32x4;

__device__ __forceinline__ unsigned pk2(float x, float y) {
  __hip_bfloat162 h = __float22bfloat162_rn(make_float2(x, y));  // RNE pack
  union { __hip_bfloat162 h; unsigned u; } c; c.h = h; return c.u;
}
__device__ __forceinline__ float bf2f(short s) {
  union { unsigned u; float f; } c; c.u = ((unsigned)(unsigned short)s) << 16; return c.f;
}

// ---------------------------------------------------------------------------
// x_spec partials (fp32): partial[b][c][k][p] = sum_n evecs[b,n,k]*area*x_in[b,n,p]
// ---------------------------------------------------------------------------
__global__ __launch_bounds__(256)
void k_spec_partial(const float* __restrict__ evecs, const float* __restrict__ xin,
                    const float* __restrict__ areas, float* __restrict__ partial)
{
  const int c = blockIdx.x, b = blockIdx.y, t = threadIdx.x;
  const int ty = t >> 4, tx = t & 15;
  __shared__ float ev[32][129];
  __shared__ float xs[32][129];
  float acc[8][8];
#pragma unroll
  for (int i = 0; i < 8; ++i)
#pragma unroll
    for (int j = 0; j < 8; ++j) acc[i][j] = 0.f;

  const float* evb = evecs + (size_t)b * N_ * K_;
  const float* xb  = xin   + (size_t)b * N_ * P_;
  const float* ab  = areas + (size_t)b * N_;

  for (int s = 0; s < CHROWS; s += 32) {
    const int n0 = c * CHROWS + s;
    __syncthreads();
#pragma unroll
    for (int i = 0; i < 4; ++i) {
      int f4 = t + i * 256;
      int r = f4 >> 5, c4 = (f4 & 31) << 2;
      int n = n0 + r;
      float4 e4 = make_float4(0.f,0.f,0.f,0.f), x4 = make_float4(0.f,0.f,0.f,0.f);
      float ar = 0.f;
      if (n < N_) {
        e4 = *(const float4*)(evb + (size_t)n * K_ + c4);
        x4 = *(const float4*)(xb  + (size_t)n * P_ + c4);
        ar = ab[n];
      }
      ev[r][c4+0] = e4.x*ar; ev[r][c4+1] = e4.y*ar; ev[r][c4+2] = e4.z*ar; ev[r][c4+3] = e4.w*ar;
      xs[r][c4+0] = x4.x;    xs[r][c4+1] = x4.y;    xs[r][c4+2] = x4.z;    xs[r][c4+3] = x4.w;
    }
    __syncthreads();
#pragma unroll 4
    for (int n = 0; n < 32; ++n) {
      float a[8], w[8];
#pragma unroll
      for (int i = 0; i < 8; ++i) a[i] = ev[n][ty*8 + i];
#pragma unroll
      for (int j = 0; j < 8; ++j) w[j] = xs[n][tx + 16*j];
#pragma unroll
      for (int i = 0; i < 8; ++i)
#pragma unroll
        for (int j = 0; j < 8; ++j) acc[i][j] = fmaf(a[i], w[j], acc[i][j]);
    }
  }
  float* po = partial + (size_t)(b * NCHUNK + c) * (K_ * P_);
#pragma unroll
  for (int i = 0; i < 8; ++i)
#pragma unroll
    for (int j = 0; j < 8; ++j)
      po[(ty*8 + i) * P_ + tx + 16*j] = acc[i][j];
}

__global__ __launch_bounds__(256)
void k_spec_reduce(const float* __restrict__ partial, const float* __restrict__ evals,
                   const float* __restrict__ times, float* __restrict__ sspecT)
{
  int idx = blockIdx.x * 256 + threadIdx.x;
  int b = idx >> 14;
  int kp = idx & 16383;
  int k = kp >> 7, p = kp & 127;
  float s = 0.f;
  const float* pb = partial + (size_t)b * NCHUNK * (K_*P_) + kp;
  for (int c = 0; c < NCHUNK; ++c) s += pb[(size_t)c * (K_*P_)];
  float tt = times[p]; tt = tt < 1e-8f ? 1e-8f : tt;
  float sc = __expf(-evals[b*K_ + k] * tt);
  sspecT[((size_t)b*P_ + p) * K_ + k] = s * sc;
}

// ---------------------------------------------------------------------------
// bf16 MFMA row-GEMM machinery.
// LDS tile: 128 rows x 16 kgroups (16B = 8 bf16), slot = r*16 + (kg ^ (r&7)).
// ---------------------------------------------------------------------------
__device__ __forceinline__ void stg_f32(uint4* __restrict__ Ls, const float* __restrict__ G,
                                        int ld, int nrows, int t)
{
#pragma unroll
  for (int i = 0; i < 4; ++i) {
    int gid = t + i * 512;
    int r = gid >> 4, kg = gid & 15;
    float4 v0 = make_float4(0.f,0.f,0.f,0.f), v1 = v0;
    if (r < nrows) {
      const float* p = G + (size_t)r * ld + kg * 8;
      v0 = *(const float4*)p;
      v1 = *(const float4*)(p + 4);
    }
    uint4 u;
    u.x = pk2(v0.x, v0.y); u.y = pk2(v0.z, v0.w);
    u.z = pk2(v1.x, v1.y); u.w = pk2(v1.z, v1.w);
    Ls[r * 16 + (kg ^ (r & 7))] = u;
  }
}

__device__ __forceinline__ void stg_bf(uint4* __restrict__ Ls,
                                       const __hip_bfloat16* __restrict__ G,
                                       int ld, int nrows, int t)
{
#pragma unroll
  for (int i = 0; i < 4; ++i) {
    int gid = t + i * 512;
    int r = gid >> 4, kg = gid & 15;
    uint4 u = make_uint4(0u,0u,0u,0u);
    if (r < nrows) u = *(const uint4*)(G + (size_t)r * ld + kg * 8);
    Ls[r * 16 + (kg ^ (r & 7))] = u;
  }
}

// one 128-K chunk of MFMA: wave (wr,wc) accumulates its 64x32 sub-tile
__device__ __forceinline__ void mfma_chunk(const uint4* AsB, const uint4* WsB,
                                           int wr, int wc, int lr, int lg,
                                           f32x4 acc[4][2])
{
  const short8* Ap = (const short8*)AsB;
  const short8* Wp = (const short8*)WsB;
#pragma unroll
  for (int kk = 0; kk < 4; ++kk) {
    int gg = kk * 4 + lg;
    short8 a[4], w[2];
#pragma unroll
    for (int m = 0; m < 4; ++m) {
      int rr = wr*64 + m*16 + lr;
      a[m] = Ap[rr*16 + (gg ^ (rr & 7))];
    }
#pragma unroll
    for (int n = 0; n < 2; ++n) {
      int rr = wc*32 + n*16 + lr;
      w[n] = Wp[rr*16 + (gg ^ (rr & 7))];
    }
#pragma unroll
    for (int m = 0; m < 4; ++m)
#pragma unroll
      for (int n = 0; n < 2; ++n)
        acc[m][n] = __builtin_amdgcn_mfma_f32_16x16x32_bf16(a[m], w[n], acc[m][n], 0, 0, 0);
  }
}

// MODE: 0 plain->bf16, 1 relu+bias (3 chunks)->bf16, 2 relu+bias->bf16, 3 bias+resid->f32
template<int MODE>
__global__ __launch_bounds__(512)
void k_rowgemm(const void* __restrict__ A0, const void* __restrict__ A1,
               const void* __restrict__ A2, int abf,
               const float* __restrict__ W, int ldw, int wbs, int nchunk,
               const float* __restrict__ bias, const float* __restrict__ resid,
               void* __restrict__ C)
{
  const int b = blockIdx.y, r0 = blockIdx.x * 128, t = threadIdx.x;
  const int l = t & 63, wid = t >> 6;
  const int wr = wid >> 2, wc = wid & 3;          // 2x4 wave grid
  const int lr = l & 15, lg = l >> 4;
  __shared__ uint4 AsB[2048];
  __shared__ uint4 WsB[2048];
  f32x4 acc[4][2];
#pragma unroll
  for (int m = 0; m < 4; ++m)
#pragma unroll
    for (int n = 0; n < 2; ++n) acc[m][n] = (f32x4)0.f;

  const float* Wb = W + (size_t)b * wbs;
  const int nrows = min(128, N_ - r0);
  const size_t aoff = (size_t)b * N_ * 128 + (size_t)r0 * 128;

  for (int kc = 0; kc < nchunk; ++kc) {
    const void* Av = (kc == 0 ? A0 : (kc == 1 ? A1 : A2));
    __syncthreads();
    if ((abf >> kc) & 1) stg_bf(AsB, (const __hip_bfloat16*)Av + aoff, 128, nrows, t);
    else                 stg_f32(AsB, (const float*)Av + aoff, 128, nrows, t);
    stg_f32(WsB, Wb + kc * 128, ldw, 128, t);
    __syncthreads();
    mfma_chunk(AsB, WsB, wr, wc, lr, lg, acc);
  }

  const size_t cb = (size_t)b * N_ * 128;
#pragma unroll
  for (int m = 0; m < 4; ++m) {
    int rowt = wr*64 + m*16 + lg*4;
#pragma unroll
    for (int r = 0; r < 4; ++r) {
      int row = r0 + rowt + r;
      if (row >= N_) continue;
#pragma unroll
      for (int n = 0; n < 2; ++n) {
        int col = wc*32 + n*16 + lr;
        float v = acc[m][n][r];
        if (MODE == 1 || MODE == 2) v = fmaxf(v + bias[col], 0.f);
        if (MODE == 3) {
          v += bias[col] + resid[cb + (size_t)row*128 + col];
          ((float*)C)[cb + (size_t)row*128 + col] = v;
        } else {
          ((__hip_bfloat16*)C)[cb + (size_t)row*128 + col] = __float2bfloat16(v);
        }
      }
    }
  }
}

// ---------------------------------------------------------------------------
// grad features (MFMA): xg <- tanh(gx*(gx@Bre^T) + gy*(gy@Bim^T)), in place over gx
// ---------------------------------------------------------------------------
__global__ __launch_bounds__(512)
void k_grad(const float* __restrict__ Bre, const float* __restrict__ Bim,
            __hip_bfloat16* __restrict__ gx, const __hip_bfloat16* __restrict__ gy)
{
  const int b = blockIdx.y, r0 = blockIdx.x * 128, t = threadIdx.x;
  const int l = t & 63, wid = t >> 6;
  const int wr = wid >> 2, wc = wid & 3;
  const int lr = l & 15, lg = l >> 4;
  __shared__ uint4 AsB[2048];
  __shared__ uint4 WsB[2048];
  f32x4 acc1[4][2], acc2[4][2];
  float g1[4][2][4], g2[4][2][4];
#pragma unroll
  for (int m = 0; m < 4; ++m)
#pragma unroll
    for (int n = 0; n < 2; ++n) { acc1[m][n] = (f32x4)0.f; acc2[m][n] = (f32x4)0.f; }

  __hip_bfloat16*       gxb = gx + (size_t)b * N_ * P_;
  const __hip_bfloat16* gyb = gy + (size_t)b * N_ * P_;
  const int nrows = min(128, N_ - r0);
  const short* Ab = (const short*)AsB;

  // pass 1: gx @ Bre^T
  stg_bf(AsB, gxb + (size_t)r0 * 128, 128, nrows, t);
  stg_f32(WsB, Bre, 128, 128, t);
  __syncthreads();
  mfma_chunk(AsB, WsB, wr, wc, lr, lg, acc1);
#pragma unroll
  for (int m = 0; m < 4; ++m)
#pragma unroll
    for (int r = 0; r < 4; ++r) {
      int rowt = wr*64 + m*16 + lg*4 + r;
#pragma unroll
      for (int n = 0; n < 2; ++n) {
        int col = wc*32 + n*16 + lr;
        g1[m][n][r] = bf2f(Ab[(rowt*16 + ((col>>3) ^ (rowt & 7)))*8 + (col & 7)]);
      }
    }
  __syncthreads();
  // pass 2: gy @ Bim^T
  stg_bf(AsB, gyb + (size_t)r0 * 128, 128, nrows, t);
  stg_f32(WsB, Bim, 128, 128, t);
  __syncthreads();
  mfma_chunk(AsB, WsB, wr, wc, lr, lg, acc2);
#pragma unroll
  for (int m = 0; m < 4; ++m)
#pragma unroll
    for (int r = 0; r < 4; ++r) {
      int rowt = wr*64 + m*16 + lg*4 + r;
#pragma unroll
      for (int n = 0; n < 2; ++n) {
        int col = wc*32 + n*16 + lr;
        g2[m][n][r] = bf2f(Ab[(rowt*16 + ((col>>3) ^ (rowt & 7)))*8 + (col & 7)]);
      }
    }

#pragma unroll
  for (int m = 0; m < 4; ++m)
#pragma unroll
    for (int r = 0; r < 4; ++r) {
      int row = r0 + wr*64 + m*16 + lg*4 + r;
      if (row >= N_) continue;
#pragma unroll
      for (int n = 0; n < 2; ++n) {
        int col = wc*32 + n*16 + lr;
        float v = tanhf(g1[m][n][r]*acc1[m][n][r] + g2[m][n][r]*acc2[m][n][r]);
        gxb[(size_t)row*128 + col] = __float2bfloat16(v);
      }
    }
}

// ---------------------------------------------------------------------------
// SpMM: count -> scan -> fill (bin-ordered col/val triplets) -> gather
// ---------------------------------------------------------------------------
__global__ void k_count(const int* __restrict__ rows, int* __restrict__ cnt)
{
  int b = blockIdx.y;
  int e = blockIdx.x * 256 + threadIdx.x;
  if (e < E_) atomicAdd(&cnt[b*N_ + rows[(size_t)b*E_ + e]], 1);
}

__global__ __launch_bounds__(256)
void k_scan(const int* __restrict__ cnt, int* __restrict__ off, int* __restrict__ pos)
{
  const int b = blockIdx.x, t = threadIdx.x;
  const int lane = t & 63, wid = t >> 6;
  __shared__ int wt[4];
  int running = 0;
  for (int base = 0; base < N_; base += 256) {
    int i = base + t;
    int v = (i < N_) ? cnt[b*N_ + i] : 0;
    int x = v;
#pragma unroll
    for (int ofs = 1; ofs < 64; ofs <<= 1) {
      int y = __shfl_up(x, ofs, 64);
      if (lane >= ofs) x += y;
    }
    if (lane == 63) wt[wid] = x;
    __syncthreads();
    int wofs = 0;
    for (int wj = 0; wj < wid; ++wj) wofs += wt[wj];
    int tot = wt[0] + wt[1] + wt[2] + wt[3];
    int excl = running + wofs + x - v;
    if (i < N_) { off[b*(N_+1) + i] = excl; pos[b*N_ + i] = excl; }
    running += tot;
    __syncthreads();
  }
  if (t == 0) off[b*(N_+1) + N_] = running;
}

// scatter (col, wx, wy) into bin order: coalesced reads, one-time scattered writes
__global__ void k_fill(const int* __restrict__ rows, const int* __restrict__ cols,
                       const float* __restrict__ vx, const float* __restrict__ vy,
                       int* __restrict__ pos, int* __restrict__ pcid,
                       float* __restrict__ pvx, float* __restrict__ pvy)
{
  int b = blockIdx.y;
  int e = blockIdx.x * 256 + threadIdx.x;
  if (e < E_) {
    size_t be = (size_t)b*E_ + e;
    int r = rows[be];
    int p = atomicAdd(&pos[b*N_ + r], 1);
    size_t bp = (size_t)b*E_ + p;
    pcid[bp] = cols[be];
    pvx[bp]  = vx[be];
    pvy[bp]  = vy[be];
  }
}

// wave per row; lane-parallel metadata prefetch + shfl broadcast;
// per-edge row gathers are independent -> deep in flight
__global__ __launch_bounds__(256)
void k_gather(const __hip_bfloat16* __restrict__ xd, const int* __restrict__ pcid,
              const float* __restrict__ pvx, const float* __restrict__ pvy,
              const int* __restrict__ off,
              __hip_bfloat16* __restrict__ gx, __hip_bfloat16* __restrict__ gy)
{
  const int b = blockIdx.y;
  const int row = (blockIdx.x * 256 + threadIdx.x) >> 6;
  const int lane = threadIdx.x & 63;
  if (row >= N_) return;
  const int s = off[b*(N_+1) + row], e = off[b*(N_+1) + row + 1];
  float ax0 = 0.f, ax1 = 0.f, ay0 = 0.f, ay1 = 0.f;
  const __hip_bfloat16* xdb = xd + (size_t)b * N_ * P_;
  const size_t bE = (size_t)b * E_;

  for (int base = s; base < e; base += 64) {
    const int cnt = min(64, e - base);
    int cid = 0; float wx = 0.f, wy = 0.f;
    if (lane < cnt) {
      cid = pcid[bE + base + lane];
      wx  = pvx[bE + base + lane];
      wy  = pvy[bE + base + lane];
    }
    for (int i = 0; i < cnt; ++i) {
      int   c  = __shfl(cid, i, 64);
      float fx = __shfl(wx,  i, 64);
      float fy = __shfl(wy,  i, 64);
      unsigned v = *(const unsigned*)(xdb + (size_t)c * P_ + lane*2);
      float x0 = bf2f((short)(v & 0xffff));
      float x1 = bf2f((short)(v >> 16));
      ax0 = fmaf(fx, x0, ax0); ax1 = fmaf(fx, x1, ax1);
      ay0 = fmaf(fy, x0, ay0); ay1 = fmaf(fy, x1, ay1);
    }
  }
  size_t o = (size_t)b * N_ * P_ + (size_t)row * P_ + lane*2;
  *(unsigned*)(gx + o) = pk2(ax0, ax1);
  *(unsigned*)(gy + o) = pk2(ay0, ay1);
}

// ---------------------------------------------------------------------------
extern "C" void kernel_launch(void* const* d_in, const int* in_sizes, int n_in,
                              void* d_out, int out_size, void* d_ws, size_t ws_size,
                              hipStream_t stream)
{
  const float* x_in  = (const float*)d_in[0];
  const float* areas = (const float*)d_in[1];
  const float* evals = (const float*)d_in[2];
  const float* evecs = (const float*)d_in[3];
  const float* gXv   = (const float*)d_in[4];
  const float* gYv   = (const float*)d_in[5];
  const int*   grows = (const int*)d_in[6];
  const int*   gcols = (const int*)d_in[7];
  const float* times = (const float*)d_in[8];
  const float* Bre   = (const float*)d_in[9];
  const float* Bim   = (const float*)d_in[10];
  const float* W1    = (const float*)d_in[11];
  const float* b1    = (const float*)d_in[12];
  const float* W2    = (const float*)d_in[13];
  const float* b2    = (const float*)d_in[14];
  const float* W3    = (const float*)d_in[15];
  const float* b3    = (const float*)d_in[16];

  float* ws = (float*)d_ws;
  // bf16 intermediates (each B*N*P bf16 = 5,120,000 floats of space)
  __hip_bfloat16* xd_bf = (__hip_bfloat16*)ws;                  // x_diffuse
  float*          part  = ws + 6000000;                         // fp32 spec partials (5.18M floats)
  __hip_bfloat16* gx_bf = (__hip_bfloat16*)(ws + 12000000);     // gx -> xg -> h2
  __hip_bfloat16* gy_bf = (__hip_bfloat16*)(ws + 18000000);     // gy -> h1

  // transient scratch in d_out's tail; dead before MLP3 writes d_out
  int*   ipos   = (int*)d_out;                      // B*N counts/cursor
  int*   ioff   = ipos + B_*N_;                     // B*(N+1) offsets
  int*   pcid   = ioff + B_*(N_+1);                 // B*E binned cols
  float* pvx    = (float*)(pcid + (size_t)B_*E_);   // B*E binned gradX vals
  float* pvy    = pvx + (size_t)B_*E_;              // B*E binned gradY vals
  float* sspecT = pvy + (size_t)B_*E_;              // B*P*K fp32
  float* out    = (float*)d_out;

  const int GB = (N_ + 127) / 128;  // 157 row blocks

  // spectral projection + scale (fused, transposed output)
  k_spec_partial<<<dim3(NCHUNK, B_), 256, 0, stream>>>(evecs, x_in, areas, part);
  k_spec_reduce<<<dim3(B_*K_*P_/256), 256, 0, stream>>>(part, evals, times, sspecT);
  // x_diffuse = evecs @ sspec   (W per-batch: wbs = K*P) -> bf16
  k_rowgemm<0><<<dim3(GB, B_), 512, 0, stream>>>(evecs, nullptr, nullptr, 0, sspecT,
                                                 128, K_*P_, 1, nullptr, nullptr, xd_bf);
  // sparse gradient via counting sort
  hipMemsetAsync(ipos, 0, (size_t)B_*N_*sizeof(int), stream);
  k_count<<<dim3(E_/256, B_), 256, 0, stream>>>(grows, ipos);
  k_scan<<<dim3(B_), 256, 0, stream>>>(ipos, ioff, ipos);
  k_fill<<<dim3(E_/256, B_), 256, 0, stream>>>(grows, gcols, gXv, gYv, ipos,
                                               pcid, pvx, pvy);
  k_gather<<<dim3(N_/4, B_), 256, 0, stream>>>(xd_bf, pcid, pvx, pvy, ioff,
                                               gx_bf, gy_bf);
  // grad features (in place over gx)
  k_grad<<<dim3(GB, B_), 512, 0, stream>>>(Bre, Bim, gx_bf, gy_bf);
  // MLP: h1 -> gy slot, h2 -> gx slot, final -> d_out
  k_rowgemm<1><<<dim3(GB, B_), 512, 0, stream>>>(x_in, xd_bf, gx_bf, 0b110, W1,
                                                 384, 0, 3, b1, nullptr, gy_bf);
  k_rowgemm<2><<<dim3(GB, B_), 512, 0, stream>>>(gy_bf, nullptr, nullptr, 1, W2,
                                                 128, 0, 1, b2, nullptr, gx_bf);
  k_rowgemm<3><<<dim3(GB, B_), 512, 0, stream>>>(gx_bf, nullptr, nullptr, 1, W3,
                                                 128, 0, 1, b3, x_in, out);
}

// Round 6
// 354.165 us; speedup vs baseline: 2.2094x; 1.0512x over previous
//
#include <hip/hip_runtime.h>
#include <hip/hip_bf16.h>
#include <cstddef>

#define B_ 4
#define N_ 20000
#define P_ 128
#define K_ 128
#define E_ 160000

constexpr int CHROWS = 224;
constexpr int NCHUNK = (N_ + CHROWS - 1) / CHROWS;  // 90

typedef __attribute__((ext_vector_type(8))) short short8;
typedef __attribute__((ext_vector_type(4))) float f32x4;

__device__ __forceinline__ unsigned pk2(float x, float y) {
  __hip_bfloat162 h = __float22bfloat162_rn(make_float2(x, y));  // RNE pack
  union { __hip_bfloat162 h; unsigned u; } c; c.h = h; return c.u;
}
__device__ __forceinline__ float bf2f(short s) {
  union { unsigned u; float f; } c; c.u = ((unsigned)(unsigned short)s) << 16; return c.f;
}

// ---------------------------------------------------------------------------
// x_spec partials (fp32): partial[b][c][k][p] = sum_{n in chunk} ev[n,k]*area*x[n,p]
// grid (NCHUNK, 2, B): blockIdx.y picks a 64-wide P half (720 blocks total)
// ---------------------------------------------------------------------------
__global__ __launch_bounds__(256)
void k_spec_partial(const float* __restrict__ evecs, const float* __restrict__ xin,
                    const float* __restrict__ areas, float* __restrict__ partial)
{
  const int c = blockIdx.x, ph = blockIdx.y, b = blockIdx.z, t = threadIdx.x;
  const int ty = t >> 4, tx = t & 15;
  __shared__ float ev[32][129];
  __shared__ float xs[32][65];
  float acc[8][4];
#pragma unroll
  for (int i = 0; i < 8; ++i)
#pragma unroll
    for (int j = 0; j < 4; ++j) acc[i][j] = 0.f;

  const float* evb = evecs + (size_t)b * N_ * K_;
  const float* xb  = xin   + (size_t)b * N_ * P_ + ph * 64;
  const float* ab  = areas + (size_t)b * N_;

  for (int s = 0; s < CHROWS; s += 32) {
    const int n0 = c * CHROWS + s;
    __syncthreads();
#pragma unroll
    for (int i = 0; i < 4; ++i) {        // evecs: 32 rows x 128 cols
      int f4 = t + i * 256;
      int r = f4 >> 5, c4 = (f4 & 31) << 2;
      int n = n0 + r;
      float4 e4 = make_float4(0.f,0.f,0.f,0.f);
      float ar = 0.f;
      if (n < N_) {
        e4 = *(const float4*)(evb + (size_t)n * K_ + c4);
        ar = ab[n];
      }
      ev[r][c4+0] = e4.x*ar; ev[r][c4+1] = e4.y*ar; ev[r][c4+2] = e4.z*ar; ev[r][c4+3] = e4.w*ar;
    }
#pragma unroll
    for (int i = 0; i < 2; ++i) {        // x half: 32 rows x 64 cols
      int f4 = t + i * 256;
      int r = f4 >> 4, c4 = (f4 & 15) << 2;
      int n = n0 + r;
      float4 x4 = make_float4(0.f,0.f,0.f,0.f);
      if (n < N_) x4 = *(const float4*)(xb + (size_t)n * P_ + c4);
      xs[r][c4+0] = x4.x; xs[r][c4+1] = x4.y; xs[r][c4+2] = x4.z; xs[r][c4+3] = x4.w;
    }
    __syncthreads();
#pragma unroll 4
    for (int n = 0; n < 32; ++n) {
      float a[8], w[4];
#pragma unroll
      for (int i = 0; i < 8; ++i) a[i] = ev[n][ty*8 + i];
#pragma unroll
      for (int j = 0; j < 4; ++j) w[j] = xs[n][tx + 16*j];
#pragma unroll
      for (int i = 0; i < 8; ++i)
#pragma unroll
        for (int j = 0; j < 4; ++j) acc[i][j] = fmaf(a[i], w[j], acc[i][j]);
    }
  }
  float* po = partial + (size_t)(b * NCHUNK + c) * (K_ * P_) + ph * 64;
#pragma unroll
  for (int i = 0; i < 8; ++i)
#pragma unroll
    for (int j = 0; j < 4; ++j)
      po[(ty*8 + i) * P_ + tx + 16*j] = acc[i][j];
}

__global__ __launch_bounds__(256)
void k_spec_reduce(const float* __restrict__ partial, const float* __restrict__ evals,
                   const float* __restrict__ times, float* __restrict__ sspecT)
{
  int idx = blockIdx.x * 256 + threadIdx.x;
  int b = idx >> 14;
  int kp = idx & 16383;
  int k = kp >> 7, p = kp & 127;
  float s = 0.f;
  const float* pb = partial + (size_t)b * NCHUNK * (K_*P_) + kp;
  for (int c = 0; c < NCHUNK; ++c) s += pb[(size_t)c * (K_*P_)];
  float tt = times[p]; tt = tt < 1e-8f ? 1e-8f : tt;
  float sc = __expf(-evals[b*K_ + k] * tt);
  sspecT[((size_t)b*P_ + p) * K_ + k] = s * sc;
}

// ---------------------------------------------------------------------------
// bf16 MFMA row-GEMM machinery.
// LDS tile: 128 rows x 16 kgroups (16B = 8 bf16), slot = r*16 + (kg ^ (r&7)).
// ---------------------------------------------------------------------------
__device__ __forceinline__ void stg_f32(uint4* __restrict__ Ls, const float* __restrict__ G,
                                        int ld, int nrows, int t)
{
#pragma unroll
  for (int i = 0; i < 4; ++i) {
    int gid = t + i * 512;
    int r = gid >> 4, kg = gid & 15;
    float4 v0 = make_float4(0.f,0.f,0.f,0.f), v1 = v0;
    if (r < nrows) {
      const float* p = G + (size_t)r * ld + kg * 8;
      v0 = *(const float4*)p;
      v1 = *(const float4*)(p + 4);
    }
    uint4 u;
    u.x = pk2(v0.x, v0.y); u.y = pk2(v0.z, v0.w);
    u.z = pk2(v1.x, v1.y); u.w = pk2(v1.z, v1.w);
    Ls[r * 16 + (kg ^ (r & 7))] = u;
  }
}

__device__ __forceinline__ void stg_bf(uint4* __restrict__ Ls,
                                       const __hip_bfloat16* __restrict__ G,
                                       int ld, int nrows, int t)
{
#pragma unroll
  for (int i = 0; i < 4; ++i) {
    int gid = t + i * 512;
    int r = gid >> 4, kg = gid & 15;
    uint4 u = make_uint4(0u,0u,0u,0u);
    if (r < nrows) u = *(const uint4*)(G + (size_t)r * ld + kg * 8);
    Ls[r * 16 + (kg ^ (r & 7))] = u;
  }
}

// one 128-K chunk of MFMA: wave (wr,wc) accumulates its 64x32 sub-tile
__device__ __forceinline__ void mfma_chunk(const uint4* AsB, const uint4* WsB,
                                           int wr, int wc, int lr, int lg,
                                           f32x4 acc[4][2])
{
  const short8* Ap = (const short8*)AsB;
  const short8* Wp = (const short8*)WsB;
#pragma unroll
  for (int kk = 0; kk < 4; ++kk) {
    int gg = kk * 4 + lg;
    short8 a[4], w[2];
#pragma unroll
    for (int m = 0; m < 4; ++m) {
      int rr = wr*64 + m*16 + lr;
      a[m] = Ap[rr*16 + (gg ^ (rr & 7))];
    }
#pragma unroll
    for (int n = 0; n < 2; ++n) {
      int rr = wc*32 + n*16 + lr;
      w[n] = Wp[rr*16 + (gg ^ (rr & 7))];
    }
#pragma unroll
    for (int m = 0; m < 4; ++m)
#pragma unroll
      for (int n = 0; n < 2; ++n)
        acc[m][n] = __builtin_amdgcn_mfma_f32_16x16x32_bf16(a[m], w[n], acc[m][n], 0, 0, 0);
  }
}

// MODE: 0 plain->bf16, 1 relu+bias (3 chunks)->bf16, 2 relu+bias->bf16, 3 bias+resid->f32
template<int MODE>
__global__ __launch_bounds__(512)
void k_rowgemm(const void* __restrict__ A0, const void* __restrict__ A1,
               const void* __restrict__ A2, int abf,
               const float* __restrict__ W, int ldw, int wbs, int nchunk,
               const float* __restrict__ bias, const float* __restrict__ resid,
               void* __restrict__ C)
{
  const int b = blockIdx.y, r0 = blockIdx.x * 128, t = threadIdx.x;
  const int l = t & 63, wid = t >> 6;
  const int wr = wid >> 2, wc = wid & 3;          // 2x4 wave grid
  const int lr = l & 15, lg = l >> 4;
  __shared__ uint4 AsB[2048];
  __shared__ uint4 WsB[2048];
  f32x4 acc[4][2];
#pragma unroll
  for (int m = 0; m < 4; ++m)
#pragma unroll
    for (int n = 0; n < 2; ++n) acc[m][n] = (f32x4)0.f;

  const float* Wb = W + (size_t)b * wbs;
  const int nrows = min(128, N_ - r0);
  const size_t aoff = (size_t)b * N_ * 128 + (size_t)r0 * 128;

  for (int kc = 0; kc < nchunk; ++kc) {
    const void* Av = (kc == 0 ? A0 : (kc == 1 ? A1 : A2));
    __syncthreads();
    if ((abf >> kc) & 1) stg_bf(AsB, (const __hip_bfloat16*)Av + aoff, 128, nrows, t);
    else                 stg_f32(AsB, (const float*)Av + aoff, 128, nrows, t);
    stg_f32(WsB, Wb + kc * 128, ldw, 128, t);
    __syncthreads();
    mfma_chunk(AsB, WsB, wr, wc, lr, lg, acc);
  }

  const size_t cb = (size_t)b * N_ * 128;
#pragma unroll
  for (int m = 0; m < 4; ++m) {
    int rowt = wr*64 + m*16 + lg*4;
#pragma unroll
    for (int r = 0; r < 4; ++r) {
      int row = r0 + rowt + r;
      if (row >= N_) continue;
#pragma unroll
      for (int n = 0; n < 2; ++n) {
        int col = wc*32 + n*16 + lr;
        float v = acc[m][n][r];
        if (MODE == 1 || MODE == 2) v = fmaxf(v + bias[col], 0.f);
        if (MODE == 3) {
          v += bias[col] + resid[cb + (size_t)row*128 + col];
          ((float*)C)[cb + (size_t)row*128 + col] = v;
        } else {
          ((__hip_bfloat16*)C)[cb + (size_t)row*128 + col] = __float2bfloat16(v);
        }
      }
    }
  }
}

// ---------------------------------------------------------------------------
// grad features (MFMA): xg <- tanh(gx*(gx@Bre^T) + gy*(gy@Bim^T)), in place over gx
// ---------------------------------------------------------------------------
__global__ __launch_bounds__(512)
void k_grad(const float* __restrict__ Bre, const float* __restrict__ Bim,
            __hip_bfloat16* __restrict__ gx, const __hip_bfloat16* __restrict__ gy)
{
  const int b = blockIdx.y, r0 = blockIdx.x * 128, t = threadIdx.x;
  const int l = t & 63, wid = t >> 6;
  const int wr = wid >> 2, wc = wid & 3;
  const int lr = l & 15, lg = l >> 4;
  __shared__ uint4 AsB[2048];
  __shared__ uint4 WsB[2048];
  f32x4 acc1[4][2], acc2[4][2];
  float g1[4][2][4], g2[4][2][4];
#pragma unroll
  for (int m = 0; m < 4; ++m)
#pragma unroll
    for (int n = 0; n < 2; ++n) { acc1[m][n] = (f32x4)0.f; acc2[m][n] = (f32x4)0.f; }

  __hip_bfloat16*       gxb = gx + (size_t)b * N_ * P_;
  const __hip_bfloat16* gyb = gy + (size_t)b * N_ * P_;
  const int nrows = min(128, N_ - r0);
  const short* Ab = (const short*)AsB;

  // pass 1: gx @ Bre^T
  stg_bf(AsB, gxb + (size_t)r0 * 128, 128, nrows, t);
  stg_f32(WsB, Bre, 128, 128, t);
  __syncthreads();
  mfma_chunk(AsB, WsB, wr, wc, lr, lg, acc1);
#pragma unroll
  for (int m = 0; m < 4; ++m)
#pragma unroll
    for (int r = 0; r < 4; ++r) {
      int rowt = wr*64 + m*16 + lg*4 + r;
#pragma unroll
      for (int n = 0; n < 2; ++n) {
        int col = wc*32 + n*16 + lr;
        g1[m][n][r] = bf2f(Ab[(rowt*16 + ((col>>3) ^ (rowt & 7)))*8 + (col & 7)]);
      }
    }
  __syncthreads();
  // pass 2: gy @ Bim^T
  stg_bf(AsB, gyb + (size_t)r0 * 128, 128, nrows, t);
  stg_f32(WsB, Bim, 128, 128, t);
  __syncthreads();
  mfma_chunk(AsB, WsB, wr, wc, lr, lg, acc2);
#pragma unroll
  for (int m = 0; m < 4; ++m)
#pragma unroll
    for (int r = 0; r < 4; ++r) {
      int rowt = wr*64 + m*16 + lg*4 + r;
#pragma unroll
      for (int n = 0; n < 2; ++n) {
        int col = wc*32 + n*16 + lr;
        g2[m][n][r] = bf2f(Ab[(rowt*16 + ((col>>3) ^ (rowt & 7)))*8 + (col & 7)]);
      }
    }

#pragma unroll
  for (int m = 0; m < 4; ++m)
#pragma unroll
    for (int r = 0; r < 4; ++r) {
      int row = r0 + wr*64 + m*16 + lg*4 + r;
      if (row >= N_) continue;
#pragma unroll
      for (int n = 0; n < 2; ++n) {
        int col = wc*32 + n*16 + lr;
        float v = tanhf(g1[m][n][r]*acc1[m][n][r] + g2[m][n][r]*acc2[m][n][r]);
        gxb[(size_t)row*128 + col] = __float2bfloat16(v);
      }
    }
}

// ---------------------------------------------------------------------------
// SpMM: count -> scan -> fill (bin-ordered col/val triplets) -> gather
// ---------------------------------------------------------------------------
__global__ void k_count(const int* __restrict__ rows, int* __restrict__ cnt)
{
  int b = blockIdx.y;
  int e = blockIdx.x * 256 + threadIdx.x;
  if (e < E_) atomicAdd(&cnt[b*N_ + rows[(size_t)b*E_ + e]], 1);
}

__global__ __launch_bounds__(256)
void k_scan(const int* __restrict__ cnt, int* __restrict__ off, int* __restrict__ pos)
{
  const int b = blockIdx.x, t = threadIdx.x;
  const int lane = t & 63, wid = t >> 6;
  __shared__ int wt[4];
  int running = 0;
  for (int base = 0; base < N_; base += 256) {
    int i = base + t;
    int v = (i < N_) ? cnt[b*N_ + i] : 0;
    int x = v;
#pragma unroll
    for (int ofs = 1; ofs < 64; ofs <<= 1) {
      int y = __shfl_up(x, ofs, 64);
      if (lane >= ofs) x += y;
    }
    if (lane == 63) wt[wid] = x;
    __syncthreads();
    int wofs = 0;
    for (int wj = 0; wj < wid; ++wj) wofs += wt[wj];
    int tot = wt[0] + wt[1] + wt[2] + wt[3];
    int excl = running + wofs + x - v;
    if (i < N_) { off[b*(N_+1) + i] = excl; pos[b*N_ + i] = excl; }
    running += tot;
    __syncthreads();
  }
  if (t == 0) off[b*(N_+1) + N_] = running;
}

// scatter (col, wx, wy) into bin order: coalesced reads, one-time scattered writes
__global__ void k_fill(const int* __restrict__ rows, const int* __restrict__ cols,
                       const float* __restrict__ vx, const float* __restrict__ vy,
                       int* __restrict__ pos, int* __restrict__ pcid,
                       float* __restrict__ pvx, float* __restrict__ pvy)
{
  int b = blockIdx.y;
  int e = blockIdx.x * 256 + threadIdx.x;
  if (e < E_) {
    size_t be = (size_t)b*E_ + e;
    int r = rows[be];
    int p = atomicAdd(&pos[b*N_ + r], 1);
    if (p >= 0 && p < E_) {            // bounds guard: no data-dependent OOB write
      size_t bp = (size_t)b*E_ + p;
      pcid[bp] = cols[be];
      pvx[bp]  = vx[be];
      pvy[bp]  = vy[be];
    }
  }
}

// wave per row; lane-parallel metadata prefetch + shfl broadcast;
// per-edge row gathers are independent -> deep in flight
__global__ __launch_bounds__(256)
void k_gather(const __hip_bfloat16* __restrict__ xd, const int* __restrict__ pcid,
              const float* __restrict__ pvx, const float* __restrict__ pvy,
              const int* __restrict__ off,
              __hip_bfloat16* __restrict__ gx, __hip_bfloat16* __restrict__ gy)
{
  const int b = blockIdx.y;
  const int row = (blockIdx.x * 256 + threadIdx.x) >> 6;
  const int lane = threadIdx.x & 63;
  if (row >= N_) return;
  const int s = off[b*(N_+1) + row], e = off[b*(N_+1) + row + 1];
  float ax0 = 0.f, ax1 = 0.f, ay0 = 0.f, ay1 = 0.f;
  const __hip_bfloat16* xdb = xd + (size_t)b * N_ * P_;
  const size_t bE = (size_t)b * E_;

  for (int base = s; base < e; base += 64) {
    const int cnt = min(64, e - base);
    int cid = 0; float wx = 0.f, wy = 0.f;
    if (lane < cnt) {
      cid = pcid[bE + base + lane];
      wx  = pvx[bE + base + lane];
      wy  = pvy[bE + base + lane];
    }
    for (int i = 0; i < cnt; ++i) {
      int   c  = __shfl(cid, i, 64);
      float fx = __shfl(wx,  i, 64);
      float fy = __shfl(wy,  i, 64);
      unsigned v = *(const unsigned*)(xdb + (size_t)c * P_ + lane*2);
      float x0 = bf2f((short)(v & 0xffff));
      float x1 = bf2f((short)(v >> 16));
      ax0 = fmaf(fx, x0, ax0); ax1 = fmaf(fx, x1, ax1);
      ay0 = fmaf(fy, x0, ay0); ay1 = fmaf(fy, x1, ay1);
    }
  }
  size_t o = (size_t)b * N_ * P_ + (size_t)row * P_ + lane*2;
  *(unsigned*)(gx + o) = pk2(ax0, ax1);
  *(unsigned*)(gy + o) = pk2(ay0, ay1);
}

// ---------------------------------------------------------------------------
extern "C" void kernel_launch(void* const* d_in, const int* in_sizes, int n_in,
                              void* d_out, int out_size, void* d_ws, size_t ws_size,
                              hipStream_t stream)
{
  const float* x_in  = (const float*)d_in[0];
  const float* areas = (const float*)d_in[1];
  const float* evals = (const float*)d_in[2];
  const float* evecs = (const float*)d_in[3];
  const float* gXv   = (const float*)d_in[4];
  const float* gYv   = (const float*)d_in[5];
  const int*   grows = (const int*)d_in[6];
  const int*   gcols = (const int*)d_in[7];
  const float* times = (const float*)d_in[8];
  const float* Bre   = (const float*)d_in[9];
  const float* Bim   = (const float*)d_in[10];
  const float* W1    = (const float*)d_in[11];
  const float* b1    = (const float*)d_in[12];
  const float* W2    = (const float*)d_in[13];
  const float* b2    = (const float*)d_in[14];
  const float* W3    = (const float*)d_in[15];
  const float* b3    = (const float*)d_in[16];

  float* ws = (float*)d_ws;
  // ws layout (float offsets) — d_out is now WRITE-ONLY (final output):
  //   xd_bf [0, 5.12M) | part [6M, 11.9M) | gx [12M, 17.12M) | gy [18M, 23.12M)
  //   scratch [24M, 26.15M): ipos | ioff | pcid | pvx | pvy | sspecT
  __hip_bfloat16* xd_bf = (__hip_bfloat16*)ws;                  // x_diffuse bf16
  float*          part  = ws + 6000000;                         // fp32 partials (NCHUNK*B*K*P = 5.90M)
  __hip_bfloat16* gx_bf = (__hip_bfloat16*)(ws + 12000000);     // gx -> xg -> h2
  __hip_bfloat16* gy_bf = (__hip_bfloat16*)(ws + 18000000);     // gy -> h1

  int*   ipos   = (int*)(ws + 24000000);            // B*N counts/cursor
  int*   ioff   = ipos + B_*N_;                     // B*(N+1) offsets
  int*   pcid   = ioff + B_*(N_+1);                 // B*E binned cols
  float* pvx    = (float*)(pcid + (size_t)B_*E_);   // B*E binned gradX vals
  float* pvy    = pvx + (size_t)B_*E_;              // B*E binned gradY vals
  float* sspecT = pvy + (size_t)B_*E_;              // B*P*K fp32
  float* out    = (float*)d_out;

  const int GB = (N_ + 127) / 128;  // 157 row blocks

  // spectral projection + scale (fused, transposed output)
  k_spec_partial<<<dim3(NCHUNK, 2, B_), 256, 0, stream>>>(evecs, x_in, areas, part);
  k_spec_reduce<<<dim3(B_*K_*P_/256), 256, 0, stream>>>(part, evals, times, sspecT);
  // x_diffuse = evecs @ sspec   (W per-batch: wbs = K*P) -> bf16
  k_rowgemm<0><<<dim3(GB, B_), 512, 0, stream>>>(evecs, nullptr, nullptr, 0, sspecT,
                                                 128, K_*P_, 1, nullptr, nullptr, xd_bf);
  // sparse gradient via counting sort
  hipMemsetAsync(ipos, 0, (size_t)B_*N_*sizeof(int), stream);
  k_count<<<dim3(E_/256, B_), 256, 0, stream>>>(grows, ipos);
  k_scan<<<dim3(B_), 256, 0, stream>>>(ipos, ioff, ipos);
  k_fill<<<dim3(E_/256, B_), 256, 0, stream>>>(grows, gcols, gXv, gYv, ipos,
                                               pcid, pvx, pvy);
  k_gather<<<dim3(N_/4, B_), 256, 0, stream>>>(xd_bf, pcid, pvx, pvy, ioff,
                                               gx_bf, gy_bf);
  // grad features (in place over gx)
  k_grad<<<dim3(GB, B_), 512, 0, stream>>>(Bre, Bim, gx_bf, gy_bf);
  // MLP: h1 -> gy slot, h2 -> gx slot, final -> d_out
  k_rowgemm<1><<<dim3(GB, B_), 512, 0, stream>>>(x_in, xd_bf, gx_bf, 0b110, W1,
                                                 384, 0, 3, b1, nullptr, gy_bf);
  k_rowgemm<2><<<dim3(GB, B_), 512, 0, stream>>>(gy_bf, nullptr, nullptr, 1, W2,
                                                 128, 0, 1, b2, nullptr, gx_bf);
  k_rowgemm<3><<<dim3(GB, B_), 512, 0, stream>>>(gx_bf, nullptr, nullptr, 1, W3,
                                                 128, 0, 1, b3, x_in, out);
}

// Round 7
// 341.248 us; speedup vs baseline: 2.2930x; 1.0379x over previous
//
#include <hip/hip_runtime.h>
#include <hip/hip_bf16.h>
#include <cstddef>

#define B_ 4
#define N_ 20000
#define P_ 128
#define K_ 128
#define E_ 160000

constexpr int NCH_S = 79;   // ceil(N/256) split-K chunks for spectral projection

typedef __attribute__((ext_vector_type(8))) short short8;
typedef __attribute__((ext_vector_type(4))) float f32x4;

__device__ __forceinline__ unsigned pk2(float x, float y) {
  __hip_bfloat162 h = __float22bfloat162_rn(make_float2(x, y));  // RNE pack
  union { __hip_bfloat162 h; unsigned u; } c; c.h = h; return c.u;
}
__device__ __forceinline__ float bf2f(short s) {
  union { unsigned u; float f; } c; c.u = ((unsigned)(unsigned short)s) << 16; return c.f;
}

// ---------------------------------------------------------------------------
// prep: transpose+scale+bf16.  evT[b][k][n] = bf16(ev[b][n][k]*area[b][n]),
//       xT[b][p][n] = bf16(x[b][n][p]).   grid (ceil(N/64), 2half*2mat, B)
// ---------------------------------------------------------------------------
__global__ __launch_bounds__(256)
void k_prep(const float* __restrict__ ev, const float* __restrict__ xin,
            const float* __restrict__ areas,
            __hip_bfloat16* __restrict__ evT, __hip_bfloat16* __restrict__ xT)
{
  const int tn = blockIdx.x, half = blockIdx.y & 1, mat = blockIdx.y >> 1;
  const int b = blockIdx.z, t = threadIdx.x;
  const int n0 = tn * 64, c0 = half * 64;
  __shared__ float ld[64][65];
  const float* src = (mat ? xin : ev) + (size_t)b * N_ * 128;
  const float* ab  = areas + (size_t)b * N_;
#pragma unroll
  for (int i = 0; i < 4; ++i) {
    int gid = t + i * 256;
    int r = gid >> 4, c4 = (gid & 15) << 2;
    int n = n0 + r;
    float4 v = make_float4(0.f, 0.f, 0.f, 0.f);
    if (n < N_) {
      v = *(const float4*)(src + (size_t)n * 128 + c0 + c4);
      if (mat == 0) { float ar = ab[n]; v.x *= ar; v.y *= ar; v.z *= ar; v.w *= ar; }
    }
    ld[r][c4] = v.x; ld[r][c4+1] = v.y; ld[r][c4+2] = v.z; ld[r][c4+3] = v.w;
  }
  __syncthreads();
  __hip_bfloat16* dst = (mat ? xT : evT) + (size_t)b * 128 * N_;
#pragma unroll
  for (int i = 0; i < 4; ++i) {
    int gid = t + i * 256;
    int cr = gid >> 4, nq = (gid & 15) << 2;
    int n = n0 + nq;
    if (n + 4 <= N_) {                      // N%4==0: never a partial quad
      uint2 u;
      u.x = pk2(ld[nq][cr],   ld[nq+1][cr]);
      u.y = pk2(ld[nq+2][cr], ld[nq+3][cr]);
      *(uint2*)(dst + (size_t)(c0 + cr) * N_ + n) = u;
    }
  }
}

// ---------------------------------------------------------------------------
// spectral projection via MFMA: part[b][c][k][p] = sum_{n in chunk c} evT[k][n]*xT[p][n]
// grid (NCH_S, B), 512 thr, 8 waves (2x4), wave sub-tile 64x32 of the 128x128 out
// ---------------------------------------------------------------------------
__device__ __forceinline__ void stg64(uint4* __restrict__ Ls,
                                      const __hip_bfloat16* __restrict__ G,
                                      int n0, int t)
{
#pragma unroll
  for (int i = 0; i < 2; ++i) {
    int gid = t + i * 512;
    int r = gid >> 3, kg = gid & 7;
    int n = n0 + kg * 8;
    uint4 u = make_uint4(0u, 0u, 0u, 0u);
    if (n < N_) u = *(const uint4*)(G + (size_t)r * N_ + n);  // N%8==0: full or none
    Ls[r * 8 + (kg ^ (r & 7))] = u;
  }
}

__global__ __launch_bounds__(512)
void k_spec_mm(const __hip_bfloat16* __restrict__ evT,
               const __hip_bfloat16* __restrict__ xT,
               float* __restrict__ part)
{
  const int c = blockIdx.x, b = blockIdx.y, t = threadIdx.x;
  const int l = t & 63, wid = t >> 6;
  const int wr = wid >> 2, wc = wid & 3;
  const int lr = l & 15, lg = l >> 4;
  __shared__ uint4 AsB[1024];
  __shared__ uint4 WsB[1024];
  f32x4 acc[4][2];
#pragma unroll
  for (int m = 0; m < 4; ++m)
#pragma unroll
    for (int n = 0; n < 2; ++n) acc[m][n] = (f32x4)0.f;

  const __hip_bfloat16* eb = evT + (size_t)b * 128 * N_;
  const __hip_bfloat16* xb = xT  + (size_t)b * 128 * N_;

  for (int s = 0; s < 4; ++s) {
    int n0 = c * 256 + s * 64;
    __syncthreads();
    stg64(AsB, eb, n0, t);
    stg64(WsB, xb, n0, t);
    __syncthreads();
    const short8* Ap = (const short8*)AsB;
    const short8* Wp = (const short8*)WsB;
#pragma unroll
    for (int kk = 0; kk < 2; ++kk) {
      int gg = kk * 4 + lg;
      short8 a[4], w[2];
#pragma unroll
      for (int m = 0; m < 4; ++m) { int rr = wr*64 + m*16 + lr; a[m] = Ap[rr*8 + (gg ^ (rr & 7))]; }
#pragma unroll
      for (int n = 0; n < 2; ++n) { int rr = wc*32 + n*16 + lr; w[n] = Wp[rr*8 + (gg ^ (rr & 7))]; }
#pragma unroll
      for (int m = 0; m < 4; ++m)
#pragma unroll
        for (int n = 0; n < 2; ++n)
          acc[m][n] = __builtin_amdgcn_mfma_f32_16x16x32_bf16(a[m], w[n], acc[m][n], 0, 0, 0);
    }
  }

  float* po = part + ((size_t)(b * NCH_S + c) << 14);
#pragma unroll
  for (int m = 0; m < 4; ++m)
#pragma unroll
    for (int r = 0; r < 4; ++r) {
      int row = wr*64 + m*16 + lg*4 + r;     // k index
#pragma unroll
      for (int n = 0; n < 2; ++n) {
        int col = wc*32 + n*16 + lr;         // p index
        po[row * 128 + col] = acc[m][n][r];
      }
    }
}

__global__ __launch_bounds__(256)
void k_spec_reduce(const float* __restrict__ partial, const float* __restrict__ evals,
                   const float* __restrict__ times, float* __restrict__ sspecT)
{
  int idx = blockIdx.x * 256 + threadIdx.x;
  int b = idx >> 14;
  int kp = idx & 16383;
  int k = kp >> 7, p = kp & 127;
  float s = 0.f;
  const float* pb = partial + (size_t)b * NCH_S * (K_*P_) + kp;
  for (int c = 0; c < NCH_S; ++c) s += pb[(size_t)c * (K_*P_)];
  float tt = times[p]; tt = tt < 1e-8f ? 1e-8f : tt;
  float sc = __expf(-evals[b*K_ + k] * tt);
  sspecT[((size_t)b*P_ + p) * K_ + k] = s * sc;
}

// ---------------------------------------------------------------------------
// bf16 MFMA row-GEMM machinery.
// LDS tile: 128 rows x 16 kgroups (16B = 8 bf16), slot = r*16 + (kg ^ (r&7)).
// ---------------------------------------------------------------------------
__device__ __forceinline__ void stg_f32(uint4* __restrict__ Ls, const float* __restrict__ G,
                                        int ld, int nrows, int t)
{
#pragma unroll
  for (int i = 0; i < 4; ++i) {
    int gid = t + i * 512;
    int r = gid >> 4, kg = gid & 15;
    float4 v0 = make_float4(0.f,0.f,0.f,0.f), v1 = v0;
    if (r < nrows) {
      const float* p = G + (size_t)r * ld + kg * 8;
      v0 = *(const float4*)p;
      v1 = *(const float4*)(p + 4);
    }
    uint4 u;
    u.x = pk2(v0.x, v0.y); u.y = pk2(v0.z, v0.w);
    u.z = pk2(v1.x, v1.y); u.w = pk2(v1.z, v1.w);
    Ls[r * 16 + (kg ^ (r & 7))] = u;
  }
}

__device__ __forceinline__ void stg_bf(uint4* __restrict__ Ls,
                                       const __hip_bfloat16* __restrict__ G,
                                       int ld, int nrows, int t)
{
#pragma unroll
  for (int i = 0; i < 4; ++i) {
    int gid = t + i * 512;
    int r = gid >> 4, kg = gid & 15;
    uint4 u = make_uint4(0u,0u,0u,0u);
    if (r < nrows) u = *(const uint4*)(G + (size_t)r * ld + kg * 8);
    Ls[r * 16 + (kg ^ (r & 7))] = u;
  }
}

// one 128-K chunk of MFMA: wave (wr,wc) accumulates its 64x32 sub-tile
__device__ __forceinline__ void mfma_chunk(const uint4* AsB, const uint4* WsB,
                                           int wr, int wc, int lr, int lg,
                                           f32x4 acc[4][2])
{
  const short8* Ap = (const short8*)AsB;
  const short8* Wp = (const short8*)WsB;
#pragma unroll
  for (int kk = 0; kk < 4; ++kk) {
    int gg = kk * 4 + lg;
    short8 a[4], w[2];
#pragma unroll
    for (int m = 0; m < 4; ++m) {
      int rr = wr*64 + m*16 + lr;
      a[m] = Ap[rr*16 + (gg ^ (rr & 7))];
    }
#pragma unroll
    for (int n = 0; n < 2; ++n) {
      int rr = wc*32 + n*16 + lr;
      w[n] = Wp[rr*16 + (gg ^ (rr & 7))];
    }
#pragma unroll
    for (int m = 0; m < 4; ++m)
#pragma unroll
      for (int n = 0; n < 2; ++n)
        acc[m][n] = __builtin_amdgcn_mfma_f32_16x16x32_bf16(a[m], w[n], acc[m][n], 0, 0, 0);
  }
}

// MODE: 0 plain->bf16, 1 relu+bias (3 chunks)->bf16, 2 relu+bias->bf16, 3 bias+resid->f32
template<int MODE>
__global__ __launch_bounds__(512)
void k_rowgemm(const void* __restrict__ A0, const void* __restrict__ A1,
               const void* __restrict__ A2, int abf,
               const float* __restrict__ W, int ldw, int wbs, int nchunk,
               const float* __restrict__ bias, const float* __restrict__ resid,
               void* __restrict__ C)
{
  const int b = blockIdx.y, r0 = blockIdx.x * 128, t = threadIdx.x;
  const int l = t & 63, wid = t >> 6;
  const int wr = wid >> 2, wc = wid & 3;          // 2x4 wave grid
  const int lr = l & 15, lg = l >> 4;
  __shared__ uint4 AsB[2048];
  __shared__ uint4 WsB[2048];
  f32x4 acc[4][2];
#pragma unroll
  for (int m = 0; m < 4; ++m)
#pragma unroll
    for (int n = 0; n < 2; ++n) acc[m][n] = (f32x4)0.f;

  const float* Wb = W + (size_t)b * wbs;
  const int nrows = min(128, N_ - r0);
  const size_t aoff = (size_t)b * N_ * 128 + (size_t)r0 * 128;

  for (int kc = 0; kc < nchunk; ++kc) {
    const void* Av = (kc == 0 ? A0 : (kc == 1 ? A1 : A2));
    __syncthreads();
    if ((abf >> kc) & 1) stg_bf(AsB, (const __hip_bfloat16*)Av + aoff, 128, nrows, t);
    else                 stg_f32(AsB, (const float*)Av + aoff, 128, nrows, t);
    stg_f32(WsB, Wb + kc * 128, ldw, 128, t);
    __syncthreads();
    mfma_chunk(AsB, WsB, wr, wc, lr, lg, acc);
  }

  const size_t cb = (size_t)b * N_ * 128;
#pragma unroll
  for (int m = 0; m < 4; ++m) {
    int rowt = wr*64 + m*16 + lg*4;
#pragma unroll
    for (int r = 0; r < 4; ++r) {
      int row = r0 + rowt + r;
      if (row >= N_) continue;
#pragma unroll
      for (int n = 0; n < 2; ++n) {
        int col = wc*32 + n*16 + lr;
        float v = acc[m][n][r];
        if (MODE == 1 || MODE == 2) v = fmaxf(v + bias[col], 0.f);
        if (MODE == 3) {
          v += bias[col] + resid[cb + (size_t)row*128 + col];
          ((float*)C)[cb + (size_t)row*128 + col] = v;
        } else {
          ((__hip_bfloat16*)C)[cb + (size_t)row*128 + col] = __float2bfloat16(v);
        }
      }
    }
  }
}

// ---------------------------------------------------------------------------
// grad features (MFMA): xg <- tanh(gx*(gx@Bre^T) + gy*(gy@Bim^T)), in place over gx
// ---------------------------------------------------------------------------
__global__ __launch_bounds__(512)
void k_grad(const float* __restrict__ Bre, const float* __restrict__ Bim,
            __hip_bfloat16* __restrict__ gx, const __hip_bfloat16* __restrict__ gy)
{
  const int b = blockIdx.y, r0 = blockIdx.x * 128, t = threadIdx.x;
  const int l = t & 63, wid = t >> 6;
  const int wr = wid >> 2, wc = wid & 3;
  const int lr = l & 15, lg = l >> 4;
  __shared__ uint4 AsB[2048];
  __shared__ uint4 WsB[2048];
  f32x4 acc1[4][2], acc2[4][2];
  float g1[4][2][4], g2[4][2][4];
#pragma unroll
  for (int m = 0; m < 4; ++m)
#pragma unroll
    for (int n = 0; n < 2; ++n) { acc1[m][n] = (f32x4)0.f; acc2[m][n] = (f32x4)0.f; }

  __hip_bfloat16*       gxb = gx + (size_t)b * N_ * P_;
  const __hip_bfloat16* gyb = gy + (size_t)b * N_ * P_;
  const int nrows = min(128, N_ - r0);
  const short* Ab = (const short*)AsB;

  // pass 1: gx @ Bre^T
  stg_bf(AsB, gxb + (size_t)r0 * 128, 128, nrows, t);
  stg_f32(WsB, Bre, 128, 128, t);
  __syncthreads();
  mfma_chunk(AsB, WsB, wr, wc, lr, lg, acc1);
#pragma unroll
  for (int m = 0; m < 4; ++m)
#pragma unroll
    for (int r = 0; r < 4; ++r) {
      int rowt = wr*64 + m*16 + lg*4 + r;
#pragma unroll
      for (int n = 0; n < 2; ++n) {
        int col = wc*32 + n*16 + lr;
        g1[m][n][r] = bf2f(Ab[(rowt*16 + ((col>>3) ^ (rowt & 7)))*8 + (col & 7)]);
      }
    }
  __syncthreads();
  // pass 2: gy @ Bim^T
  stg_bf(AsB, gyb + (size_t)r0 * 128, 128, nrows, t);
  stg_f32(WsB, Bim, 128, 128, t);
  __syncthreads();
  mfma_chunk(AsB, WsB, wr, wc, lr, lg, acc2);
#pragma unroll
  for (int m = 0; m < 4; ++m)
#pragma unroll
    for (int r = 0; r < 4; ++r) {
      int rowt = wr*64 + m*16 + lg*4 + r;
#pragma unroll
      for (int n = 0; n < 2; ++n) {
        int col = wc*32 + n*16 + lr;
        g2[m][n][r] = bf2f(Ab[(rowt*16 + ((col>>3) ^ (rowt & 7)))*8 + (col & 7)]);
      }
    }

#pragma unroll
  for (int m = 0; m < 4; ++m)
#pragma unroll
    for (int r = 0; r < 4; ++r) {
      int row = r0 + wr*64 + m*16 + lg*4 + r;
      if (row >= N_) continue;
#pragma unroll
      for (int n = 0; n < 2; ++n) {
        int col = wc*32 + n*16 + lr;
        float v = tanhf(g1[m][n][r]*acc1[m][n][r] + g2[m][n][r]*acc2[m][n][r]);
        gxb[(size_t)row*128 + col] = __float2bfloat16(v);
      }
    }
}

// ---------------------------------------------------------------------------
// SpMM: count -> scan -> fill (bin-ordered col/val triplets) -> gather
// ---------------------------------------------------------------------------
__global__ void k_count(const int* __restrict__ rows, int* __restrict__ cnt)
{
  int b = blockIdx.y;
  int e = blockIdx.x * 256 + threadIdx.x;
  if (e < E_) atomicAdd(&cnt[b*N_ + rows[(size_t)b*E_ + e]], 1);
}

__global__ __launch_bounds__(256)
void k_scan(const int* __restrict__ cnt, int* __restrict__ off, int* __restrict__ pos)
{
  const int b = blockIdx.x, t = threadIdx.x;
  const int lane = t & 63, wid = t >> 6;
  __shared__ int wt[4];
  int running = 0;
  for (int base = 0; base < N_; base += 256) {
    int i = base + t;
    int v = (i < N_) ? cnt[b*N_ + i] : 0;
    int x = v;
#pragma unroll
    for (int ofs = 1; ofs < 64; ofs <<= 1) {
      int y = __shfl_up(x, ofs, 64);
      if (lane >= ofs) x += y;
    }
    if (lane == 63) wt[wid] = x;
    __syncthreads();
    int wofs = 0;
    for (int wj = 0; wj < wid; ++wj) wofs += wt[wj];
    int tot = wt[0] + wt[1] + wt[2] + wt[3];
    int excl = running + wofs + x - v;
    if (i < N_) { off[b*(N_+1) + i] = excl; pos[b*N_ + i] = excl; }
    running += tot;
    __syncthreads();
  }
  if (t == 0) off[b*(N_+1) + N_] = running;
}

// scatter (col, wx, wy) into bin order: coalesced reads, one-time scattered writes
__global__ void k_fill(const int* __restrict__ rows, const int* __restrict__ cols,
                       const float* __restrict__ vx, const float* __restrict__ vy,
                       int* __restrict__ pos, int* __restrict__ pcid,
                       float* __restrict__ pvx, float* __restrict__ pvy)
{
  int b = blockIdx.y;
  int e = blockIdx.x * 256 + threadIdx.x;
  if (e < E_) {
    size_t be = (size_t)b*E_ + e;
    int r = rows[be];
    int p = atomicAdd(&pos[b*N_ + r], 1);
    if (p >= 0 && p < E_) {            // bounds guard: no data-dependent OOB write
      size_t bp = (size_t)b*E_ + p;
      pcid[bp] = cols[be];
      pvx[bp]  = vx[be];
      pvy[bp]  = vy[be];
    }
  }
}

// wave per row; lane-parallel metadata prefetch + shfl broadcast;
// per-edge row gathers are independent -> deep in flight
__global__ __launch_bounds__(256)
void k_gather(const __hip_bfloat16* __restrict__ xd, const int* __restrict__ pcid,
              const float* __restrict__ pvx, const float* __restrict__ pvy,
              const int* __restrict__ off,
              __hip_bfloat16* __restrict__ gx, __hip_bfloat16* __restrict__ gy)
{
  const int b = blockIdx.y;
  const int row = (blockIdx.x * 256 + threadIdx.x) >> 6;
  const int lane = threadIdx.x & 63;
  if (row >= N_) return;
  const int s = off[b*(N_+1) + row], e = off[b*(N_+1) + row + 1];
  float ax0 = 0.f, ax1 = 0.f, ay0 = 0.f, ay1 = 0.f;
  const __hip_bfloat16* xdb = xd + (size_t)b * N_ * P_;
  const size_t bE = (size_t)b * E_;

  for (int base = s; base < e; base += 64) {
    const int cnt = min(64, e - base);
    int cid = 0; float wx = 0.f, wy = 0.f;
    if (lane < cnt) {
      cid = pcid[bE + base + lane];
      wx  = pvx[bE + base + lane];
      wy  = pvy[bE + base + lane];
    }
    for (int i = 0; i < cnt; ++i) {
      int   c  = __shfl(cid, i, 64);
      float fx = __shfl(wx,  i, 64);
      float fy = __shfl(wy,  i, 64);
      unsigned v = *(const unsigned*)(xdb + (size_t)c * P_ + lane*2);
      float x0 = bf2f((short)(v & 0xffff));
      float x1 = bf2f((short)(v >> 16));
      ax0 = fmaf(fx, x0, ax0); ax1 = fmaf(fx, x1, ax1);
      ay0 = fmaf(fy, x0, ay0); ay1 = fmaf(fy, x1, ay1);
    }
  }
  size_t o = (size_t)b * N_ * P_ + (size_t)row * P_ + lane*2;
  *(unsigned*)(gx + o) = pk2(ax0, ax1);
  *(unsigned*)(gy + o) = pk2(ay0, ay1);
}

// ---------------------------------------------------------------------------
extern "C" void kernel_launch(void* const* d_in, const int* in_sizes, int n_in,
                              void* d_out, int out_size, void* d_ws, size_t ws_size,
                              hipStream_t stream)
{
  const float* x_in  = (const float*)d_in[0];
  const float* areas = (const float*)d_in[1];
  const float* evals = (const float*)d_in[2];
  const float* evecs = (const float*)d_in[3];
  const float* gXv   = (const float*)d_in[4];
  const float* gYv   = (const float*)d_in[5];
  const int*   grows = (const int*)d_in[6];
  const int*   gcols = (const int*)d_in[7];
  const float* times = (const float*)d_in[8];
  const float* Bre   = (const float*)d_in[9];
  const float* Bim   = (const float*)d_in[10];
  const float* W1    = (const float*)d_in[11];
  const float* b1    = (const float*)d_in[12];
  const float* W2    = (const float*)d_in[13];
  const float* b2    = (const float*)d_in[14];
  const float* W3    = (const float*)d_in[15];
  const float* b3    = (const float*)d_in[16];

  float* ws = (float*)d_ws;
  // ws layout (float offsets) — d_out WRITE-ONLY:
  //   xd_bf [0, 5.12M) | part [6M, 11.18M) | gx [12M, 17.12M) | gy [18M, 23.12M)
  //   scratch [24M, 26.15M): ipos | ioff | pcid | pvx | pvy | sspecT
  // evT/xT live in the gx/gy slots (dead until k_gather overwrites them).
  __hip_bfloat16* xd_bf = (__hip_bfloat16*)ws;                  // x_diffuse bf16
  float*          part  = ws + 6000000;                         // fp32 partials (NCH_S*B*K*P = 5.18M)
  __hip_bfloat16* gx_bf = (__hip_bfloat16*)(ws + 12000000);     // evT -> gx -> xg -> h2
  __hip_bfloat16* gy_bf = (__hip_bfloat16*)(ws + 18000000);     // xT  -> gy -> h1
  __hip_bfloat16* evT   = gx_bf;
  __hip_bfloat16* xT    = gy_bf;

  int*   ipos   = (int*)(ws + 24000000);            // B*N counts/cursor
  int*   ioff   = ipos + B_*N_;                     // B*(N+1) offsets
  int*   pcid   = ioff + B_*(N_+1);                 // B*E binned cols
  float* pvx    = (float*)(pcid + (size_t)B_*E_);   // B*E binned gradX vals
  float* pvy    = pvx + (size_t)B_*E_;              // B*E binned gradY vals
  float* sspecT = pvy + (size_t)B_*E_;              // B*P*K fp32
  float* out    = (float*)d_out;

  const int GB = (N_ + 127) / 128;  // 157 row blocks
  const int TN = (N_ + 63) / 64;    // 313 transpose tiles

  // spectral projection: transpose-prep -> MFMA split-K -> reduce+scale
  k_prep<<<dim3(TN, 4, B_), 256, 0, stream>>>(evecs, x_in, areas, evT, xT);
  k_spec_mm<<<dim3(NCH_S, B_), 512, 0, stream>>>(evT, xT, part);
  k_spec_reduce<<<dim3(B_*K_*P_/256), 256, 0, stream>>>(part, evals, times, sspecT);
  // x_diffuse = evecs @ sspec   (W per-batch: wbs = K*P) -> bf16
  k_rowgemm<0><<<dim3(GB, B_), 512, 0, stream>>>(evecs, nullptr, nullptr, 0, sspecT,
                                                 128, K_*P_, 1, nullptr, nullptr, xd_bf);
  // sparse gradient via counting sort
  hipMemsetAsync(ipos, 0, (size_t)B_*N_*sizeof(int), stream);
  k_count<<<dim3(E_/256, B_), 256, 0, stream>>>(grows, ipos);
  k_scan<<<dim3(B_), 256, 0, stream>>>(ipos, ioff, ipos);
  k_fill<<<dim3(E_/256, B_), 256, 0, stream>>>(grows, gcols, gXv, gYv, ipos,
                                               pcid, pvx, pvy);
  k_gather<<<dim3(N_/4, B_), 256, 0, stream>>>(xd_bf, pcid, pvx, pvy, ioff,
                                               gx_bf, gy_bf);
  // grad features (in place over gx)
  k_grad<<<dim3(GB, B_), 512, 0, stream>>>(Bre, Bim, gx_bf, gy_bf);
  // MLP: h1 -> gy slot, h2 -> gx slot, final -> d_out
  k_rowgemm<1><<<dim3(GB, B_), 512, 0, stream>>>(x_in, xd_bf, gx_bf, 0b110, W1,
                                                 384, 0, 3, b1, nullptr, gy_bf);
  k_rowgemm<2><<<dim3(GB, B_), 512, 0, stream>>>(gy_bf, nullptr, nullptr, 1, W2,
                                                 128, 0, 1, b2, nullptr, gx_bf);
  k_rowgemm<3><<<dim3(GB, B_), 512, 0, stream>>>(gx_bf, nullptr, nullptr, 1, W3,
                                                 128, 0, 1, b3, x_in, out);
}